// Round 4
// baseline (234.591 us; speedup 1.0000x reference)
//
#include <hip/hip_runtime.h>
#include <math.h>

#define B_  1024
#define S_  50
#define E_  512
#define L_  1024
#define D_  10
#define NN  1023   // N_NODES
#define LN_EPS 1e-5f
#define NBLK 72          // chain kernel grid (9 row-tiles x 8 col-tiles of 64x64)
#define APPLY_TILES 128  // 16 x 8 tiles for the 1024x512 batch apply

typedef short short8 __attribute__((ext_vector_type(8)));
typedef float f32x4  __attribute__((ext_vector_type(4)));

union PackU { unsigned int u[4]; short8 s; };

// Split 8 f32 into bf16 hi (truncation; lo captures remainder exactly) and
// bf16 lo (RNE). 3-term product error ~2^-16, 4-term ~2^-17.
__device__ inline void split8(const float r[8], short8& hi, short8& lo) {
    PackU H, L;
#pragma unroll
    for (int q = 0; q < 4; ++q) {
        const unsigned int u0 = __float_as_uint(r[2*q+0]);
        const unsigned int u1 = __float_as_uint(r[2*q+1]);
        H.u[q] = (u0 >> 16) | (u1 & 0xFFFF0000u);
        const float h0 = __uint_as_float(u0 & 0xFFFF0000u);
        const float h1 = __uint_as_float(u1 & 0xFFFF0000u);
        const float l0 = r[2*q+0] - h0;
        const float l1 = r[2*q+1] - h1;
        unsigned int p;
        asm("v_cvt_pk_bf16_f32 %0, %1, %2" : "=v"(p) : "v"(l0), "v"(l1));
        L.u[q] = p;
    }
    hi = H.s; lo = L.s;
}

// ---------------- Kernel A: embedding gather + mean + LayerNorm (+ctr zero) --------
__global__ __launch_bounds__(256) void k_embed_ln(const int* __restrict__ ids,
                                                  const float* __restrict__ emb,
                                                  float* __restrict__ x,
                                                  unsigned* __restrict__ ctr) {
    if (blockIdx.x == 0 && threadIdx.x == 0) {
        __hip_atomic_store(ctr, 0u, __ATOMIC_RELAXED, __HIP_MEMORY_SCOPE_AGENT);
    }
    const int b = blockIdx.x;
    const int t = threadIdx.x;
    float a0 = 0.f, a1 = 0.f;
    const int* idr = ids + b * S_;
#pragma unroll 5
    for (int s = 0; s < S_; ++s) {
        const float2 v = *reinterpret_cast<const float2*>(emb + (long)idr[s] * E_ + 2 * t);
        a0 += v.x;
        a1 += v.y;
    }
    a0 *= (1.f / S_);
    a1 *= (1.f / S_);

    __shared__ float red[256];
    red[t] = a0 + a1;
    __syncthreads();
    for (int off = 128; off > 0; off >>= 1) {
        if (t < off) red[t] += red[t + off];
        __syncthreads();
    }
    const float mean = red[0] * (1.f / E_);
    __syncthreads();
    const float d0 = a0 - mean, d1 = a1 - mean;
    red[t] = d0 * d0 + d1 * d1;
    __syncthreads();
    for (int off = 128; off > 0; off >>= 1) {
        if (t < off) red[t] += red[t + off];
        __syncthreads();
    }
    const float var = red[0] * (1.f / E_);
    const float inv = 1.f / sqrtf(var + LN_EPS);
    float2 o; o.x = d0 * inv; o.y = d1 * inv;
    *reinterpret_cast<float2*>(x + b * E_ + 2 * t) = o;
}

// ---------------- grid barrier (all NBLK blocks co-resident: 72 << 256 CUs) --------
__device__ inline void gbar(unsigned* ctr, unsigned target) {
    __syncthreads();
    __threadfence();   // release our stores to device scope
    if (threadIdx.x == 0) {
        __hip_atomic_fetch_add(ctr, 1u, __ATOMIC_RELEASE, __HIP_MEMORY_SCOPE_AGENT);
        while (__hip_atomic_load(ctr, __ATOMIC_ACQUIRE, __HIP_MEMORY_SCOPE_AGENT) < target) {
            __builtin_amdgcn_s_sleep(2);
        }
    }
    __syncthreads();
    __threadfence();   // acquire: invalidate L1 so we see other CUs' stores
}

// ---- one 64x64 compose tile: C = A(513x512) @ B(512x512) [+ B.c on row 512] ----
// A normal (row-major, k-contig); B via Bt (n-major, k-contig). Writes C normal
// (513x512) and Ct (512x512 transposed matrix part). 4-term split product.
__device__ inline void compose_std(const float* __restrict__ A,
                                   const float* __restrict__ Bt,
                                   const float* __restrict__ Bbias,
                                   float* __restrict__ C,
                                   float* __restrict__ Ct,
                                   int br, int bc, int wid, int r_lo, int kg) {
    const int row_base = br * 64 + (wid >> 1) * 32;
    const int col_base = bc * 64 + (wid & 1) * 32;
    f32x4 acc[2][2] = {};
    for (int kt = 0; kt < E_; kt += 32) {
        const int ks = kt + kg * 8;
        short8 ah[2], al[2], bhf[2], blf[2];
#pragma unroll
        for (int i = 0; i < 2; ++i) {
            int row = row_base + i * 16 + r_lo;
            if (row > E_) row = E_;      // clamp into the 513 valid rows
            const float4 v0 = *reinterpret_cast<const float4*>(A + (long)row * E_ + ks);
            const float4 v1 = *reinterpret_cast<const float4*>(A + (long)row * E_ + ks + 4);
            const float rr[8] = {v0.x, v0.y, v0.z, v0.w, v1.x, v1.y, v1.z, v1.w};
            split8(rr, ah[i], al[i]);
        }
#pragma unroll
        for (int j = 0; j < 2; ++j) {
            const int c = col_base + j * 16 + r_lo;
            const float4 v0 = *reinterpret_cast<const float4*>(Bt + (long)c * E_ + ks);
            const float4 v1 = *reinterpret_cast<const float4*>(Bt + (long)c * E_ + ks + 4);
            const float rr[8] = {v0.x, v0.y, v0.z, v0.w, v1.x, v1.y, v1.z, v1.w};
            split8(rr, bhf[j], blf[j]);
        }
#pragma unroll
        for (int i = 0; i < 2; ++i)
#pragma unroll
            for (int j = 0; j < 2; ++j) {
                acc[i][j] = __builtin_amdgcn_mfma_f32_16x16x32_bf16(ah[i], bhf[j], acc[i][j], 0, 0, 0);
                acc[i][j] = __builtin_amdgcn_mfma_f32_16x16x32_bf16(ah[i], blf[j], acc[i][j], 0, 0, 0);
                acc[i][j] = __builtin_amdgcn_mfma_f32_16x16x32_bf16(al[i], bhf[j], acc[i][j], 0, 0, 0);
                acc[i][j] = __builtin_amdgcn_mfma_f32_16x16x32_bf16(al[i], blf[j], acc[i][j], 0, 0, 0);
            }
    }
    // C/D layout: col = lane&15, row = kg*4 + reg (within each 16x16 frag).
#pragma unroll
    for (int j = 0; j < 2; ++j) {
        const int col = col_base + j * 16 + r_lo;
        const float bb = Bbias[col];
#pragma unroll
        for (int i = 0; i < 2; ++i) {
            const int row0 = row_base + i * 16 + kg * 4;
            float4 tv;
#pragma unroll
            for (int r2 = 0; r2 < 4; ++r2) {
                const int row = row0 + r2;
                float v = acc[i][j][r2];
                if (row == E_) v += bb;                 // bias row epilogue
                if (row <= E_) C[(long)row * E_ + col] = v;
                ((float*)&tv)[r2] = v;
            }
            if (row0 + 3 < E_) {                        // transposed matrix part only
                *reinterpret_cast<float4*>(Ct + (long)col * E_ + row0) = tv;
            }
        }
    }
}

// ---------------- Kernel CH: full affine power chain + batch apply ----------------
// step0: P2 = [Wh;bh]^∘2 (B read strided from Wh directly)
// step1: P4 = P2^∘2   step2: P8 = P4^∘2   step3: P10 = P2 ∘ P8
// step4: xb = xa @ M10 + c10 (tile loop, 3-term split)
__global__ __launch_bounds__(256) void k_chain(const float* __restrict__ Wh,
                                               const float* __restrict__ bh,
                                               float* __restrict__ Q0, float* __restrict__ T0,
                                               float* __restrict__ Q1, float* __restrict__ T1,
                                               float* __restrict__ Q2, float* __restrict__ T2,
                                               float* __restrict__ Q3, float* __restrict__ T3,
                                               const float* __restrict__ xa,
                                               float* __restrict__ xb,
                                               unsigned* __restrict__ ctr) {
    const int tid  = threadIdx.x;
    const int wid  = tid >> 6;
    const int lane = tid & 63;
    const int r_lo = lane & 15;
    const int kg   = lane >> 4;
    const int bid  = blockIdx.x;       // 0..71
    const int br   = bid >> 3;         // 0..8
    const int bc   = bid & 7;          // 0..7

    // ---- step 0: P2 ----
    {
        const int row_base = br * 64 + (wid >> 1) * 32;
        const int col_base = bc * 64 + (wid & 1) * 32;
        f32x4 acc[2][2] = {};
        for (int kt = 0; kt < E_; kt += 32) {
            const int ks = kt + kg * 8;
            short8 ah[2], al[2], bhf[2], blf[2];
#pragma unroll
            for (int i = 0; i < 2; ++i) {
                const int row = row_base + i * 16 + r_lo;
                const float* ap = (row < E_) ? (Wh + (long)row * E_ + ks) : (bh + ks);
                const float4 v0 = *reinterpret_cast<const float4*>(ap);
                const float4 v1 = *reinterpret_cast<const float4*>(ap + 4);
                const float rr[8] = {v0.x, v0.y, v0.z, v0.w, v1.x, v1.y, v1.z, v1.w};
                split8(rr, ah[i], al[i]);
            }
#pragma unroll
            for (int j = 0; j < 2; ++j) {
                const int c = col_base + j * 16 + r_lo;
                float rr[8];
#pragma unroll
                for (int q = 0; q < 8; ++q) rr[q] = Wh[(long)(ks + q) * E_ + c];
                split8(rr, bhf[j], blf[j]);
            }
#pragma unroll
            for (int i = 0; i < 2; ++i)
#pragma unroll
                for (int j = 0; j < 2; ++j) {
                    acc[i][j] = __builtin_amdgcn_mfma_f32_16x16x32_bf16(ah[i], bhf[j], acc[i][j], 0, 0, 0);
                    acc[i][j] = __builtin_amdgcn_mfma_f32_16x16x32_bf16(ah[i], blf[j], acc[i][j], 0, 0, 0);
                    acc[i][j] = __builtin_amdgcn_mfma_f32_16x16x32_bf16(al[i], bhf[j], acc[i][j], 0, 0, 0);
                    acc[i][j] = __builtin_amdgcn_mfma_f32_16x16x32_bf16(al[i], blf[j], acc[i][j], 0, 0, 0);
                }
        }
#pragma unroll
        for (int j = 0; j < 2; ++j) {
            const int col = col_base + j * 16 + r_lo;
            const float bb = bh[col];
#pragma unroll
            for (int i = 0; i < 2; ++i) {
                const int row0 = row_base + i * 16 + kg * 4;
                float4 tv;
#pragma unroll
                for (int r2 = 0; r2 < 4; ++r2) {
                    const int row = row0 + r2;
                    float v = acc[i][j][r2];
                    if (row == E_) v += bb;
                    if (row <= E_) Q0[(long)row * E_ + col] = v;
                    ((float*)&tv)[r2] = v;
                }
                if (row0 + 3 < E_) {
                    *reinterpret_cast<float4*>(T0 + (long)col * E_ + row0) = tv;
                }
            }
        }
    }

    // ---- steps 1..3 ----
    const float* Aarr[3]  = {Q0, Q1, Q2};
    const float* Btarr[3] = {T0, T1, T0};
    const float* Bbarr[3] = {Q0 + (long)E_ * E_, Q1 + (long)E_ * E_, Q0 + (long)E_ * E_};
    float* Carr[3]  = {Q1, Q2, Q3};
    float* Ctarr[3] = {T1, T2, T3};
#pragma unroll 1
    for (int s = 0; s < 3; ++s) {
        gbar(ctr, (unsigned)(NBLK * (s + 1)));
        compose_std(Aarr[s], Btarr[s], Bbarr[s], Carr[s], Ctarr[s], br, bc, wid, r_lo, kg);
    }

    // ---- step 4: batch apply, tile loop over 128 tiles ----
    gbar(ctr, (unsigned)(NBLK * 4));
    const float* bias = Q3 + (long)E_ * E_;
    for (int t = bid; t < APPLY_TILES; t += NBLK) {
        const int tr = t >> 3, tc = t & 7;
        const int row_base = tr * 64 + (wid >> 1) * 32;
        const int col_base = tc * 64 + (wid & 1) * 32;
        f32x4 acc[2][2] = {};
        for (int kt = 0; kt < E_; kt += 32) {
            const int ks = kt + kg * 8;
            short8 ah[2], al[2], bhf[2], blf[2];
#pragma unroll
            for (int i = 0; i < 2; ++i) {
                const int row = row_base + i * 16 + r_lo;
                const float4 v0 = *reinterpret_cast<const float4*>(xa + (long)row * E_ + ks);
                const float4 v1 = *reinterpret_cast<const float4*>(xa + (long)row * E_ + ks + 4);
                const float rr[8] = {v0.x, v0.y, v0.z, v0.w, v1.x, v1.y, v1.z, v1.w};
                split8(rr, ah[i], al[i]);
            }
#pragma unroll
            for (int j = 0; j < 2; ++j) {
                const int c = col_base + j * 16 + r_lo;
                const float4 v0 = *reinterpret_cast<const float4*>(T3 + (long)c * E_ + ks);
                const float4 v1 = *reinterpret_cast<const float4*>(T3 + (long)c * E_ + ks + 4);
                const float rr[8] = {v0.x, v0.y, v0.z, v0.w, v1.x, v1.y, v1.z, v1.w};
                split8(rr, bhf[j], blf[j]);
            }
#pragma unroll
            for (int i = 0; i < 2; ++i)
#pragma unroll
                for (int j = 0; j < 2; ++j) {
                    acc[i][j] = __builtin_amdgcn_mfma_f32_16x16x32_bf16(ah[i], bhf[j], acc[i][j], 0, 0, 0);
                    acc[i][j] = __builtin_amdgcn_mfma_f32_16x16x32_bf16(ah[i], blf[j], acc[i][j], 0, 0, 0);
                    acc[i][j] = __builtin_amdgcn_mfma_f32_16x16x32_bf16(al[i], bhf[j], acc[i][j], 0, 0, 0);
                }
        }
#pragma unroll
        for (int j = 0; j < 2; ++j) {
            const int col = col_base + j * 16 + r_lo;
            const float bb = bias[col];
#pragma unroll
            for (int i = 0; i < 2; ++i) {
#pragma unroll
                for (int r2 = 0; r2 < 4; ++r2) {
                    const int row = row_base + i * 16 + kg * 4 + r2;
                    xb[(long)row * E_ + col] = acc[i][j][r2] + bb;
                }
            }
        }
    }
}

// ---------------- Kernel C: theta logit-difference GEMM (split-bf16 MFMA) ----------
__global__ __launch_bounds__(256) void k_theta_gemm(const float* __restrict__ X,
                                                    const float* __restrict__ thW,
                                                    const float* __restrict__ thb,
                                                    float* __restrict__ Sm) {
    const int tid  = threadIdx.x;
    const int wid  = tid >> 6;
    const int lane = tid & 63;
    const int r_lo = lane & 15;
    const int kg   = lane >> 4;
    const int row_base = blockIdx.x * 64 + (wid >> 1) * 32;
    const int col_base = blockIdx.y * 64 + (wid & 1) * 32;

    f32x4 acc[2][2] = {};

#pragma unroll 2
    for (int kt = 0; kt < E_; kt += 32) {
        const int ks = kt + kg * 8;
        short8 ah[2], al[2], bhf[2], blf[2];
#pragma unroll
        for (int i = 0; i < 2; ++i) {
            const int row = row_base + i * 16 + r_lo;
            const float4 v0 = *reinterpret_cast<const float4*>(&X[(long)row * E_ + ks]);
            const float4 v1 = *reinterpret_cast<const float4*>(&X[(long)row * E_ + ks + 4]);
            const float rr[8] = {v0.x, v0.y, v0.z, v0.w, v1.x, v1.y, v1.z, v1.w};
            split8(rr, ah[i], al[i]);
        }
#pragma unroll
        for (int j = 0; j < 2; ++j) {
            int n = col_base + j * 16 + r_lo;
            if (n > NN - 1) n = NN - 1;
            const float* bp = thW + (long)n * (2 * E_) + ks * 2;
            const float4 q0 = *reinterpret_cast<const float4*>(bp);
            const float4 q1 = *reinterpret_cast<const float4*>(bp + 4);
            const float4 q2 = *reinterpret_cast<const float4*>(bp + 8);
            const float4 q3 = *reinterpret_cast<const float4*>(bp + 12);
            const float rr[8] = {q0.y - q0.x, q0.w - q0.z, q1.y - q1.x, q1.w - q1.z,
                                 q2.y - q2.x, q2.w - q2.z, q3.y - q3.x, q3.w - q3.z};
            split8(rr, bhf[j], blf[j]);
        }
#pragma unroll
        for (int i = 0; i < 2; ++i)
#pragma unroll
            for (int j = 0; j < 2; ++j) {
                acc[i][j] = __builtin_amdgcn_mfma_f32_16x16x32_bf16(ah[i], bhf[j], acc[i][j], 0, 0, 0);
                acc[i][j] = __builtin_amdgcn_mfma_f32_16x16x32_bf16(ah[i], blf[j], acc[i][j], 0, 0, 0);
                acc[i][j] = __builtin_amdgcn_mfma_f32_16x16x32_bf16(al[i], bhf[j], acc[i][j], 0, 0, 0);
            }
    }

#pragma unroll
    for (int j = 0; j < 2; ++j) {
        const int col = col_base + j * 16 + r_lo;
        const int cc = (col > NN - 1) ? (NN - 1) : col;
        const float bb = thb[2 * cc + 1] - thb[2 * cc + 0];
#pragma unroll
        for (int i = 0; i < 2; ++i) {
#pragma unroll
            for (int r2 = 0; r2 < 4; ++r2) {
                const int row = row_base + i * 16 + kg * 4 + r2;
                if (col < NN) {
                    Sm[(long)row * NN + col] = acc[i][j][r2] + bb;
                }
            }
        }
    }
}

// ---------------- Kernel D: tree cumulative-product of path sigmoids ----------------
__global__ __launch_bounds__(256) void k_leaf_tree(const float* __restrict__ Sm,
                                                   float* __restrict__ out) {
    __shared__ float buf[2][L_];
    const int b = blockIdx.x;
    const int tid = threadIdx.x;
    const float* srow = Sm + b * NN;
    if (tid == 0) buf[0][0] = 1.f;
    __syncthreads();
    int cur = 0;
    for (int t = 0; t < D_; ++t) {
        const int cnt = 1 << t;
        const int base = cnt - 1;
        for (int j = tid; j < cnt; j += 256) {
            const float z = srow[base + j];
            const float s = 1.f / (1.f + __expf(-z));
            const float a = buf[cur][j];
            buf[cur ^ 1][2*j + 1] = a * s;
            buf[cur ^ 1][2*j + 0] = a - a * s;
        }
        __syncthreads();
        cur ^= 1;
    }
    reinterpret_cast<float4*>(out + b * L_)[tid] =
        reinterpret_cast<const float4*>(buf[cur])[tid];
}

extern "C" void kernel_launch(void* const* d_in, const int* in_sizes, int n_in,
                              void* d_out, int out_size, void* d_ws, size_t ws_size,
                              hipStream_t stream) {
    const int*   ids = (const int*)d_in[0];
    const float* emb = (const float*)d_in[1];
    const float* Wh  = (const float*)d_in[2];
    const float* bh  = (const float*)d_in[3];
    const float* thW = (const float*)d_in[4];
    const float* thb = (const float*)d_in[5];
    float* out = (float*)d_out;

    char* ws = (char*)d_ws;
    float* xa = (float*)(ws);                      // 2 MB
    float* xb = (float*)(ws + (2u << 20));         // 2 MB
    float* sm = (float*)(ws + (4u << 20));         // ~4.19 MB
    const size_t QS = 0x140000;                    // 1.25 MB per 513x512 normal slot
    float* Q0 = (float*)(ws + (9u << 20));             // P2
    float* Q1 = (float*)(ws + (9u << 20) + QS);        // P4
    float* Q2 = (float*)(ws + (9u << 20) + 2 * QS);    // P8
    float* Q3 = (float*)(ws + (9u << 20) + 3 * QS);    // P10
    float* T0 = (float*)(ws + (16u << 20));                  // P2^T
    float* T1 = (float*)(ws + (16u << 20) + (1u << 20));     // P4^T
    float* T2 = (float*)(ws + (16u << 20) + (2u << 20));     // P8^T
    float* T3 = (float*)(ws + (16u << 20) + (3u << 20));     // P10^T
    unsigned* ctr = (unsigned*)(ws + (24u << 20));

    // 1) embedding mean + LN (also zeroes the chain barrier counter)
    k_embed_ln<<<B_, 256, 0, stream>>>(ids, emb, xa, ctr);

    // 2) affine power chain + batch apply, one kernel with internal grid barriers
    k_chain<<<NBLK, 256, 0, stream>>>(Wh, bh, Q0, T0, Q1, T1, Q2, T2, Q3, T3, xa, xb, ctr);

    // 3) theta logit-difference GEMM
    k_theta_gemm<<<dim3(B_/64, (NN + 63)/64), 256, 0, stream>>>(xb, thW, thb, sm);

    // 4) leaf products via tree
    k_leaf_tree<<<B_, 256, 0, stream>>>(sm, out);
}

// Round 5
// 175.382 us; speedup vs baseline: 1.3376x; 1.3376x over previous
//
#include <hip/hip_runtime.h>
#include <math.h>

#define B_  1024
#define S_  50
#define E_  512
#define L_  1024
#define D_  10
#define NN  1023   // N_NODES
#define LN_EPS 1e-5f

typedef short short8 __attribute__((ext_vector_type(8)));
typedef float f32x4  __attribute__((ext_vector_type(4)));

union PackU { unsigned int u[4]; short8 s; };

// Split 8 f32 into bf16 hi (truncation; lo captures remainder exactly) and
// bf16 lo (RNE). 3-term product error ~2^-16, 4-term ~2^-17.
__device__ inline void split8(const float r[8], short8& hi, short8& lo) {
    PackU H, L;
#pragma unroll
    for (int q = 0; q < 4; ++q) {
        const unsigned int u0 = __float_as_uint(r[2*q+0]);
        const unsigned int u1 = __float_as_uint(r[2*q+1]);
        H.u[q] = (u0 >> 16) | (u1 & 0xFFFF0000u);
        const float h0 = __uint_as_float(u0 & 0xFFFF0000u);
        const float h1 = __uint_as_float(u1 & 0xFFFF0000u);
        const float l0 = r[2*q+0] - h0;
        const float l1 = r[2*q+1] - h1;
        unsigned int p;
        asm("v_cvt_pk_bf16_f32 %0, %1, %2" : "=v"(p) : "v"(l0), "v"(l1));
        L.u[q] = p;
    }
    hi = H.s; lo = L.s;
}

// ---------------- Kernel A: embedding gather + mean + LayerNorm ----------------
__global__ __launch_bounds__(256) void k_embed_ln(const int* __restrict__ ids,
                                                  const float* __restrict__ emb,
                                                  float* __restrict__ x) {
    const int b = blockIdx.x;
    const int t = threadIdx.x;
    float a0 = 0.f, a1 = 0.f;
    const int* idr = ids + b * S_;
#pragma unroll 5
    for (int s = 0; s < S_; ++s) {
        const float2 v = *reinterpret_cast<const float2*>(emb + (long)idr[s] * E_ + 2 * t);
        a0 += v.x;
        a1 += v.y;
    }
    a0 *= (1.f / S_);
    a1 *= (1.f / S_);

    __shared__ float red[256];
    red[t] = a0 + a1;
    __syncthreads();
    for (int off = 128; off > 0; off >>= 1) {
        if (t < off) red[t] += red[t + off];
        __syncthreads();
    }
    const float mean = red[0] * (1.f / E_);
    __syncthreads();
    const float d0 = a0 - mean, d1 = a1 - mean;
    red[t] = d0 * d0 + d1 * d1;
    __syncthreads();
    for (int off = 128; off > 0; off >>= 1) {
        if (t < off) red[t] += red[t + off];
        __syncthreads();
    }
    const float var = red[0] * (1.f / E_);
    const float inv = 1.f / sqrtf(var + LN_EPS);
    float2 o; o.x = d0 * inv; o.y = d1 * inv;
    *reinterpret_cast<float2*>(x + b * E_ + 2 * t) = o;
}

// ---------------- Kernel C0: P2 = [Wh;bh] ∘ [Wh;bh]  (split-bf16 MFMA, 4-term) -----
// A rows (513) read from Wh/bh (k-contig); B columns read strided from Wh.
// Writes Q0 (513x512 normal) and T0 (512x512 transposed matrix part).
__global__ __launch_bounds__(256) void k_compose0(const float* __restrict__ Wh,
                                                  const float* __restrict__ bh,
                                                  float* __restrict__ Q0,
                                                  float* __restrict__ T0) {
    const int tid  = threadIdx.x;
    const int wid  = tid >> 6;
    const int lane = tid & 63;
    const int r_lo = lane & 15;
    const int kg   = lane >> 4;
    const int row_base = blockIdx.x * 64 + (wid >> 1) * 32;
    const int col_base = blockIdx.y * 64 + (wid & 1) * 32;
    f32x4 acc[2][2] = {};
    for (int kt = 0; kt < E_; kt += 32) {
        const int ks = kt + kg * 8;
        short8 ah[2], al[2], bhf[2], blf[2];
#pragma unroll
        for (int i = 0; i < 2; ++i) {
            const int row = row_base + i * 16 + r_lo;
            const float* ap = (row < E_) ? (Wh + (long)row * E_ + ks) : (bh + ks);
            const float4 v0 = *reinterpret_cast<const float4*>(ap);
            const float4 v1 = *reinterpret_cast<const float4*>(ap + 4);
            const float rr[8] = {v0.x, v0.y, v0.z, v0.w, v1.x, v1.y, v1.z, v1.w};
            split8(rr, ah[i], al[i]);
        }
#pragma unroll
        for (int j = 0; j < 2; ++j) {
            const int c = col_base + j * 16 + r_lo;
            float rr[8];
#pragma unroll
            for (int q = 0; q < 8; ++q) rr[q] = Wh[(long)(ks + q) * E_ + c];
            split8(rr, bhf[j], blf[j]);
        }
#pragma unroll
        for (int i = 0; i < 2; ++i)
#pragma unroll
            for (int j = 0; j < 2; ++j) {
                acc[i][j] = __builtin_amdgcn_mfma_f32_16x16x32_bf16(ah[i], bhf[j], acc[i][j], 0, 0, 0);
                acc[i][j] = __builtin_amdgcn_mfma_f32_16x16x32_bf16(ah[i], blf[j], acc[i][j], 0, 0, 0);
                acc[i][j] = __builtin_amdgcn_mfma_f32_16x16x32_bf16(al[i], bhf[j], acc[i][j], 0, 0, 0);
                acc[i][j] = __builtin_amdgcn_mfma_f32_16x16x32_bf16(al[i], blf[j], acc[i][j], 0, 0, 0);
            }
    }
#pragma unroll
    for (int j = 0; j < 2; ++j) {
        const int col = col_base + j * 16 + r_lo;
        const float bb = bh[col];
#pragma unroll
        for (int i = 0; i < 2; ++i) {
            const int row0 = row_base + i * 16 + kg * 4;
            float4 tv;
#pragma unroll
            for (int r2 = 0; r2 < 4; ++r2) {
                const int row = row0 + r2;
                float v = acc[i][j][r2];
                if (row == E_) v += bb;
                if (row <= E_) Q0[(long)row * E_ + col] = v;
                ((float*)&tv)[r2] = v;
            }
            if (row0 + 3 < E_) {
                *reinterpret_cast<float4*>(T0 + (long)col * E_ + row0) = tv;
            }
        }
    }
}

// ---------------- Kernel CS: compose C = A(513x512) ∘then B  (4-term split) --------
// A normal (k-contig rows); B via Bt (n-major, k-contig). Bias row epilogue adds
// B.c. Writes C normal and Ct transposed.
__global__ __launch_bounds__(256) void k_compose(const float* __restrict__ A,
                                                 const float* __restrict__ Bt,
                                                 const float* __restrict__ Bbias,
                                                 float* __restrict__ C,
                                                 float* __restrict__ Ct) {
    const int tid  = threadIdx.x;
    const int wid  = tid >> 6;
    const int lane = tid & 63;
    const int r_lo = lane & 15;
    const int kg   = lane >> 4;
    const int row_base = blockIdx.x * 64 + (wid >> 1) * 32;
    const int col_base = blockIdx.y * 64 + (wid & 1) * 32;
    f32x4 acc[2][2] = {};
    for (int kt = 0; kt < E_; kt += 32) {
        const int ks = kt + kg * 8;
        short8 ah[2], al[2], bhf[2], blf[2];
#pragma unroll
        for (int i = 0; i < 2; ++i) {
            int row = row_base + i * 16 + r_lo;
            if (row > E_) row = E_;
            const float4 v0 = *reinterpret_cast<const float4*>(A + (long)row * E_ + ks);
            const float4 v1 = *reinterpret_cast<const float4*>(A + (long)row * E_ + ks + 4);
            const float rr[8] = {v0.x, v0.y, v0.z, v0.w, v1.x, v1.y, v1.z, v1.w};
            split8(rr, ah[i], al[i]);
        }
#pragma unroll
        for (int j = 0; j < 2; ++j) {
            const int c = col_base + j * 16 + r_lo;
            const float4 v0 = *reinterpret_cast<const float4*>(Bt + (long)c * E_ + ks);
            const float4 v1 = *reinterpret_cast<const float4*>(Bt + (long)c * E_ + ks + 4);
            const float rr[8] = {v0.x, v0.y, v0.z, v0.w, v1.x, v1.y, v1.z, v1.w};
            split8(rr, bhf[j], blf[j]);
        }
#pragma unroll
        for (int i = 0; i < 2; ++i)
#pragma unroll
            for (int j = 0; j < 2; ++j) {
                acc[i][j] = __builtin_amdgcn_mfma_f32_16x16x32_bf16(ah[i], bhf[j], acc[i][j], 0, 0, 0);
                acc[i][j] = __builtin_amdgcn_mfma_f32_16x16x32_bf16(ah[i], blf[j], acc[i][j], 0, 0, 0);
                acc[i][j] = __builtin_amdgcn_mfma_f32_16x16x32_bf16(al[i], bhf[j], acc[i][j], 0, 0, 0);
                acc[i][j] = __builtin_amdgcn_mfma_f32_16x16x32_bf16(al[i], blf[j], acc[i][j], 0, 0, 0);
            }
    }
#pragma unroll
    for (int j = 0; j < 2; ++j) {
        const int col = col_base + j * 16 + r_lo;
        const float bb = Bbias[col];
#pragma unroll
        for (int i = 0; i < 2; ++i) {
            const int row0 = row_base + i * 16 + kg * 4;
            float4 tv;
#pragma unroll
            for (int r2 = 0; r2 < 4; ++r2) {
                const int row = row0 + r2;
                float v = acc[i][j][r2];
                if (row == E_) v += bb;
                if (row <= E_) C[(long)row * E_ + col] = v;
                ((float*)&tv)[r2] = v;
            }
            if (row0 + 3 < E_) {
                *reinterpret_cast<float4*>(Ct + (long)col * E_ + row0) = tv;
            }
        }
    }
}

// ---------------- Kernel AP: xb = xa @ M10 + c10  (3-term split) -------------------
__global__ __launch_bounds__(256) void k_apply(const float* __restrict__ xa,
                                               const float* __restrict__ T3,
                                               const float* __restrict__ bias,
                                               float* __restrict__ xb) {
    const int tid  = threadIdx.x;
    const int wid  = tid >> 6;
    const int lane = tid & 63;
    const int r_lo = lane & 15;
    const int kg   = lane >> 4;
    const int row_base = blockIdx.x * 64 + (wid >> 1) * 32;
    const int col_base = blockIdx.y * 64 + (wid & 1) * 32;
    f32x4 acc[2][2] = {};
#pragma unroll 2
    for (int kt = 0; kt < E_; kt += 32) {
        const int ks = kt + kg * 8;
        short8 ah[2], al[2], bhf[2], blf[2];
#pragma unroll
        for (int i = 0; i < 2; ++i) {
            const int row = row_base + i * 16 + r_lo;
            const float4 v0 = *reinterpret_cast<const float4*>(xa + (long)row * E_ + ks);
            const float4 v1 = *reinterpret_cast<const float4*>(xa + (long)row * E_ + ks + 4);
            const float rr[8] = {v0.x, v0.y, v0.z, v0.w, v1.x, v1.y, v1.z, v1.w};
            split8(rr, ah[i], al[i]);
        }
#pragma unroll
        for (int j = 0; j < 2; ++j) {
            const int c = col_base + j * 16 + r_lo;
            const float4 v0 = *reinterpret_cast<const float4*>(T3 + (long)c * E_ + ks);
            const float4 v1 = *reinterpret_cast<const float4*>(T3 + (long)c * E_ + ks + 4);
            const float rr[8] = {v0.x, v0.y, v0.z, v0.w, v1.x, v1.y, v1.z, v1.w};
            split8(rr, bhf[j], blf[j]);
        }
#pragma unroll
        for (int i = 0; i < 2; ++i)
#pragma unroll
            for (int j = 0; j < 2; ++j) {
                acc[i][j] = __builtin_amdgcn_mfma_f32_16x16x32_bf16(ah[i], bhf[j], acc[i][j], 0, 0, 0);
                acc[i][j] = __builtin_amdgcn_mfma_f32_16x16x32_bf16(ah[i], blf[j], acc[i][j], 0, 0, 0);
                acc[i][j] = __builtin_amdgcn_mfma_f32_16x16x32_bf16(al[i], bhf[j], acc[i][j], 0, 0, 0);
            }
    }
#pragma unroll
    for (int j = 0; j < 2; ++j) {
        const int col = col_base + j * 16 + r_lo;
        const float bb = bias[col];
#pragma unroll
        for (int i = 0; i < 2; ++i) {
#pragma unroll
            for (int r2 = 0; r2 < 4; ++r2) {
                const int row = row_base + i * 16 + kg * 4 + r2;
                xb[(long)row * E_ + col] = acc[i][j][r2] + bb;
            }
        }
    }
}

// ---------------- Kernel C: theta logit-difference GEMM (split-bf16 MFMA) ----------
__global__ __launch_bounds__(256) void k_theta_gemm(const float* __restrict__ X,
                                                    const float* __restrict__ thW,
                                                    const float* __restrict__ thb,
                                                    float* __restrict__ Sm) {
    const int tid  = threadIdx.x;
    const int wid  = tid >> 6;
    const int lane = tid & 63;
    const int r_lo = lane & 15;
    const int kg   = lane >> 4;
    const int row_base = blockIdx.x * 64 + (wid >> 1) * 32;
    const int col_base = blockIdx.y * 64 + (wid & 1) * 32;

    f32x4 acc[2][2] = {};

#pragma unroll 2
    for (int kt = 0; kt < E_; kt += 32) {
        const int ks = kt + kg * 8;
        short8 ah[2], al[2], bhf[2], blf[2];
#pragma unroll
        for (int i = 0; i < 2; ++i) {
            const int row = row_base + i * 16 + r_lo;
            const float4 v0 = *reinterpret_cast<const float4*>(&X[(long)row * E_ + ks]);
            const float4 v1 = *reinterpret_cast<const float4*>(&X[(long)row * E_ + ks + 4]);
            const float rr[8] = {v0.x, v0.y, v0.z, v0.w, v1.x, v1.y, v1.z, v1.w};
            split8(rr, ah[i], al[i]);
        }
#pragma unroll
        for (int j = 0; j < 2; ++j) {
            int n = col_base + j * 16 + r_lo;
            if (n > NN - 1) n = NN - 1;
            const float* bp = thW + (long)n * (2 * E_) + ks * 2;
            const float4 q0 = *reinterpret_cast<const float4*>(bp);
            const float4 q1 = *reinterpret_cast<const float4*>(bp + 4);
            const float4 q2 = *reinterpret_cast<const float4*>(bp + 8);
            const float4 q3 = *reinterpret_cast<const float4*>(bp + 12);
            const float rr[8] = {q0.y - q0.x, q0.w - q0.z, q1.y - q1.x, q1.w - q1.z,
                                 q2.y - q2.x, q2.w - q2.z, q3.y - q3.x, q3.w - q3.z};
            split8(rr, bhf[j], blf[j]);
        }
#pragma unroll
        for (int i = 0; i < 2; ++i)
#pragma unroll
            for (int j = 0; j < 2; ++j) {
                acc[i][j] = __builtin_amdgcn_mfma_f32_16x16x32_bf16(ah[i], bhf[j], acc[i][j], 0, 0, 0);
                acc[i][j] = __builtin_amdgcn_mfma_f32_16x16x32_bf16(ah[i], blf[j], acc[i][j], 0, 0, 0);
                acc[i][j] = __builtin_amdgcn_mfma_f32_16x16x32_bf16(al[i], bhf[j], acc[i][j], 0, 0, 0);
            }
    }

#pragma unroll
    for (int j = 0; j < 2; ++j) {
        const int col = col_base + j * 16 + r_lo;
        const int cc = (col > NN - 1) ? (NN - 1) : col;
        const float bb = thb[2 * cc + 1] - thb[2 * cc + 0];
#pragma unroll
        for (int i = 0; i < 2; ++i) {
#pragma unroll
            for (int r2 = 0; r2 < 4; ++r2) {
                const int row = row_base + i * 16 + kg * 4 + r2;
                if (col < NN) {
                    Sm[(long)row * NN + col] = acc[i][j][r2] + bb;
                }
            }
        }
    }
}

// ---------------- Kernel D: tree cumulative-product of path sigmoids ----------------
__global__ __launch_bounds__(256) void k_leaf_tree(const float* __restrict__ Sm,
                                                   float* __restrict__ out) {
    __shared__ float buf[2][L_];
    const int b = blockIdx.x;
    const int tid = threadIdx.x;
    const float* srow = Sm + b * NN;
    if (tid == 0) buf[0][0] = 1.f;
    __syncthreads();
    int cur = 0;
    for (int t = 0; t < D_; ++t) {
        const int cnt = 1 << t;
        const int base = cnt - 1;
        for (int j = tid; j < cnt; j += 256) {
            const float z = srow[base + j];
            const float s = 1.f / (1.f + __expf(-z));
            const float a = buf[cur][j];
            buf[cur ^ 1][2*j + 1] = a * s;
            buf[cur ^ 1][2*j + 0] = a - a * s;
        }
        __syncthreads();
        cur ^= 1;
    }
    reinterpret_cast<float4*>(out + b * L_)[tid] =
        reinterpret_cast<const float4*>(buf[cur])[tid];
}

extern "C" void kernel_launch(void* const* d_in, const int* in_sizes, int n_in,
                              void* d_out, int out_size, void* d_ws, size_t ws_size,
                              hipStream_t stream) {
    const int*   ids = (const int*)d_in[0];
    const float* emb = (const float*)d_in[1];
    const float* Wh  = (const float*)d_in[2];
    const float* bh  = (const float*)d_in[3];
    const float* thW = (const float*)d_in[4];
    const float* thb = (const float*)d_in[5];
    float* out = (float*)d_out;

    char* ws = (char*)d_ws;
    float* xa = (float*)(ws);                      // 2 MB
    float* xb = (float*)(ws + (2u << 20));         // 2 MB
    float* sm = (float*)(ws + (4u << 20));         // ~4.19 MB
    const size_t QS = 0x140000;                    // 1.25 MB per 513x512 normal slot
    float* Q0 = (float*)(ws + (9u << 20));             // P2
    float* Q1 = (float*)(ws + (9u << 20) + QS);        // P4
    float* Q2 = (float*)(ws + (9u << 20) + 2 * QS);    // P8
    float* Q3 = (float*)(ws + (9u << 20) + 3 * QS);    // P10
    float* T0 = (float*)(ws + (16u << 20));                  // P2^T
    float* T1 = (float*)(ws + (16u << 20) + (1u << 20));     // P4^T
    float* T2 = (float*)(ws + (16u << 20) + (2u << 20));     // P8^T
    float* T3 = (float*)(ws + (16u << 20) + (3u << 20));     // P10^T

    const dim3 cgrid(9, 8);   // 64x64 tiles over 513x512

    // 1) embedding mean + LN
    k_embed_ln<<<B_, 256, 0, stream>>>(ids, emb, xa);

    // 2) affine power chain (each ~0.27 GFLOP, split-bf16 4-term MFMA)
    k_compose0<<<cgrid, 256, 0, stream>>>(Wh, bh, Q0, T0);                          // P2
    k_compose<<<cgrid, 256, 0, stream>>>(Q0, T0, Q0 + (long)E_*E_, Q1, T1);         // P4
    k_compose<<<cgrid, 256, 0, stream>>>(Q1, T1, Q1 + (long)E_*E_, Q2, T2);         // P8
    k_compose<<<cgrid, 256, 0, stream>>>(Q2, T0, Q0 + (long)E_*E_, Q3, T3);         // P10

    // 3) batch apply: xb = xa @ M10 + c10
    k_apply<<<dim3(B_/64, E_/64), 256, 0, stream>>>(xa, T3, Q3 + (long)E_*E_, xb);

    // 4) theta logit-difference GEMM
    k_theta_gemm<<<dim3(B_/64, (NN + 63)/64), 256, 0, stream>>>(xb, thW, thb, sm);

    // 5) leaf products via tree
    k_leaf_tree<<<B_, 256, 0, stream>>>(sm, out);
}

// Round 6
// 149.497 us; speedup vs baseline: 1.5692x; 1.1732x over previous
//
#include <hip/hip_runtime.h>
#include <math.h>

#define B_  1024
#define S_  50
#define E_  512
#define L_  1024
#define D_  10
#define NN  1023   // N_NODES
#define LN_EPS 1e-5f
#define CBLK 72    // compose tile blocks (9 x 8 of 64x64 over 513x512)

typedef short short8 __attribute__((ext_vector_type(8)));
typedef float f32x4  __attribute__((ext_vector_type(4)));

union PackU { unsigned int u[4]; short8 s; };

// Split 8 f32 into bf16 hi (truncation; lo captures remainder exactly) and
// bf16 lo (RNE). 3-term product error ~2^-16, 4-term ~2^-17.
__device__ inline void split8(const float r[8], short8& hi, short8& lo) {
    PackU H, L;
#pragma unroll
    for (int q = 0; q < 4; ++q) {
        const unsigned int u0 = __float_as_uint(r[2*q+0]);
        const unsigned int u1 = __float_as_uint(r[2*q+1]);
        H.u[q] = (u0 >> 16) | (u1 & 0xFFFF0000u);
        const float h0 = __uint_as_float(u0 & 0xFFFF0000u);
        const float h1 = __uint_as_float(u1 & 0xFFFF0000u);
        const float l0 = r[2*q+0] - h0;
        const float l1 = r[2*q+1] - h1;
        unsigned int p;
        asm("v_cvt_pk_bf16_f32 %0, %1, %2" : "=v"(p) : "v"(l0), "v"(l1));
        L.u[q] = p;
    }
    hi = H.s; lo = L.s;
}

// ---------------- embed quarter: one block = one batch row --------------------------
__device__ inline void do_embed_row(const int* __restrict__ ids,
                                    const float* __restrict__ emb,
                                    float* __restrict__ x, int b) {
    const int t = threadIdx.x;
    float a0 = 0.f, a1 = 0.f;
    const int* idr = ids + b * S_;
#pragma unroll 5
    for (int s = 0; s < S_; ++s) {
        const float2 v = *reinterpret_cast<const float2*>(emb + (long)idr[s] * E_ + 2 * t);
        a0 += v.x;
        a1 += v.y;
    }
    a0 *= (1.f / S_);
    a1 *= (1.f / S_);

    __shared__ float red[256];
    red[t] = a0 + a1;
    __syncthreads();
    for (int off = 128; off > 0; off >>= 1) {
        if (t < off) red[t] += red[t + off];
        __syncthreads();
    }
    const float mean = red[0] * (1.f / E_);
    __syncthreads();
    const float d0 = a0 - mean, d1 = a1 - mean;
    red[t] = d0 * d0 + d1 * d1;
    __syncthreads();
    for (int off = 128; off > 0; off >>= 1) {
        if (t < off) red[t] += red[t + off];
        __syncthreads();
    }
    const float var = red[0] * (1.f / E_);
    const float inv = 1.f / sqrtf(var + LN_EPS);
    float2 o; o.x = d0 * inv; o.y = d1 * inv;
    *reinterpret_cast<float2*>(x + b * E_ + 2 * t) = o;
}

// ---------------- one 64x64 compose tile (4-term split-bf16 MFMA) -------------------
// step 0: P2 = [Wh;bh]∘[Wh;bh]   (A from Wh/bh rows, B strided from Wh cols)
// step 1: P4 = P2∘P2             (A=Q0, Bt=T0, bias=Q0.c)
// step 2: P8 = P4∘P4             (A=Q1, Bt=T1, bias=Q1.c)
// step 3: P10 = P8 ∘then P2      (A=Q2, Bt=T0, bias=Q0.c)
__device__ inline void do_compose(int step,
                                  const float* __restrict__ Wh, const float* __restrict__ bh,
                                  float* __restrict__ Q0, float* __restrict__ T0,
                                  float* __restrict__ Q1, float* __restrict__ T1,
                                  float* __restrict__ Q2, float* __restrict__ T2,
                                  float* __restrict__ Q3, float* __restrict__ T3,
                                  int bid) {
    const int tid  = threadIdx.x;
    const int wid  = tid >> 6;
    const int lane = tid & 63;
    const int r_lo = lane & 15;
    const int kg   = lane >> 4;
    const int br   = bid >> 3;
    const int bc   = bid & 7;
    const int row_base = br * 64 + (wid >> 1) * 32;
    const int col_base = bc * 64 + (wid & 1) * 32;

    const float* A;  const float* Bt;  const float* Bbias;
    float* C;  float* Ct;
    if (step == 1)      { A = Q0; Bt = T0; Bbias = Q0 + (long)E_*E_; C = Q1; Ct = T1; }
    else if (step == 2) { A = Q1; Bt = T1; Bbias = Q1 + (long)E_*E_; C = Q2; Ct = T2; }
    else                { A = Q2; Bt = T0; Bbias = Q0 + (long)E_*E_; C = Q3; Ct = T3; }

    f32x4 acc[2][2] = {};
    for (int kt = 0; kt < E_; kt += 32) {
        const int ks = kt + kg * 8;
        short8 ah[2], al[2], bhf[2], blf[2];
#pragma unroll
        for (int i = 0; i < 2; ++i) {
            int row = row_base + i * 16 + r_lo;
            const float* ap;
            if (step == 0) {
                ap = (row < E_) ? (Wh + (long)row * E_ + ks) : (bh + ks);
            } else {
                if (row > E_) row = E_;
                ap = A + (long)row * E_ + ks;
            }
            const float4 v0 = *reinterpret_cast<const float4*>(ap);
            const float4 v1 = *reinterpret_cast<const float4*>(ap + 4);
            const float rr[8] = {v0.x, v0.y, v0.z, v0.w, v1.x, v1.y, v1.z, v1.w};
            split8(rr, ah[i], al[i]);
        }
#pragma unroll
        for (int j = 0; j < 2; ++j) {
            const int c = col_base + j * 16 + r_lo;
            float rr[8];
            if (step == 0) {
#pragma unroll
                for (int q = 0; q < 8; ++q) rr[q] = Wh[(long)(ks + q) * E_ + c];
            } else {
                const float4 v0 = *reinterpret_cast<const float4*>(Bt + (long)c * E_ + ks);
                const float4 v1 = *reinterpret_cast<const float4*>(Bt + (long)c * E_ + ks + 4);
                rr[0]=v0.x; rr[1]=v0.y; rr[2]=v0.z; rr[3]=v0.w;
                rr[4]=v1.x; rr[5]=v1.y; rr[6]=v1.z; rr[7]=v1.w;
            }
            split8(rr, bhf[j], blf[j]);
        }
#pragma unroll
        for (int i = 0; i < 2; ++i)
#pragma unroll
            for (int j = 0; j < 2; ++j) {
                acc[i][j] = __builtin_amdgcn_mfma_f32_16x16x32_bf16(ah[i], bhf[j], acc[i][j], 0, 0, 0);
                acc[i][j] = __builtin_amdgcn_mfma_f32_16x16x32_bf16(ah[i], blf[j], acc[i][j], 0, 0, 0);
                acc[i][j] = __builtin_amdgcn_mfma_f32_16x16x32_bf16(al[i], bhf[j], acc[i][j], 0, 0, 0);
                acc[i][j] = __builtin_amdgcn_mfma_f32_16x16x32_bf16(al[i], blf[j], acc[i][j], 0, 0, 0);
            }
    }
    if (step == 0) { C = Q0; Ct = T0; Bbias = bh; }
#pragma unroll
    for (int j = 0; j < 2; ++j) {
        const int col = col_base + j * 16 + r_lo;
        const float bb = Bbias[col];
#pragma unroll
        for (int i = 0; i < 2; ++i) {
            const int row0 = row_base + i * 16 + kg * 4;
            float4 tv;
#pragma unroll
            for (int r2 = 0; r2 < 4; ++r2) {
                const int row = row0 + r2;
                float v = acc[i][j][r2];
                if (row == E_) v += bb;
                if (row <= E_) C[(long)row * E_ + col] = v;
                ((float*)&tv)[r2] = v;
            }
            if (row0 + 3 < E_) {
                *reinterpret_cast<float4*>(Ct + (long)col * E_ + row0) = tv;
            }
        }
    }
}

// ---------------- Fused kernel: compose step + embed quarter ------------------------
// blocks [0, CBLK): compose tile; blocks [CBLK, CBLK+256): embed rows step*256+...
__global__ __launch_bounds__(256) void k_fused(int step,
                                               const float* __restrict__ Wh,
                                               const float* __restrict__ bh,
                                               float* __restrict__ Q0, float* __restrict__ T0,
                                               float* __restrict__ Q1, float* __restrict__ T1,
                                               float* __restrict__ Q2, float* __restrict__ T2,
                                               float* __restrict__ Q3, float* __restrict__ T3,
                                               const int* __restrict__ ids,
                                               const float* __restrict__ emb,
                                               float* __restrict__ xa) {
    const int bid = blockIdx.x;
    if (bid < CBLK) {
        do_compose(step, Wh, bh, Q0, T0, Q1, T1, Q2, T2, Q3, T3, bid);
    } else {
        do_embed_row(ids, emb, xa, step * 256 + (bid - CBLK));
    }
}

// ---------------- Kernel AP: xb = xa @ M10 + c10  (3-term split) -------------------
__global__ __launch_bounds__(256) void k_apply(const float* __restrict__ xa,
                                               const float* __restrict__ T3,
                                               const float* __restrict__ bias,
                                               float* __restrict__ xb) {
    const int tid  = threadIdx.x;
    const int wid  = tid >> 6;
    const int lane = tid & 63;
    const int r_lo = lane & 15;
    const int kg   = lane >> 4;
    const int row_base = blockIdx.x * 64 + (wid >> 1) * 32;
    const int col_base = blockIdx.y * 64 + (wid & 1) * 32;
    f32x4 acc[2][2] = {};
#pragma unroll 2
    for (int kt = 0; kt < E_; kt += 32) {
        const int ks = kt + kg * 8;
        short8 ah[2], al[2], bhf[2], blf[2];
#pragma unroll
        for (int i = 0; i < 2; ++i) {
            const int row = row_base + i * 16 + r_lo;
            const float4 v0 = *reinterpret_cast<const float4*>(xa + (long)row * E_ + ks);
            const float4 v1 = *reinterpret_cast<const float4*>(xa + (long)row * E_ + ks + 4);
            const float rr[8] = {v0.x, v0.y, v0.z, v0.w, v1.x, v1.y, v1.z, v1.w};
            split8(rr, ah[i], al[i]);
        }
#pragma unroll
        for (int j = 0; j < 2; ++j) {
            const int c = col_base + j * 16 + r_lo;
            const float4 v0 = *reinterpret_cast<const float4*>(T3 + (long)c * E_ + ks);
            const float4 v1 = *reinterpret_cast<const float4*>(T3 + (long)c * E_ + ks + 4);
            const float rr[8] = {v0.x, v0.y, v0.z, v0.w, v1.x, v1.y, v1.z, v1.w};
            split8(rr, bhf[j], blf[j]);
        }
#pragma unroll
        for (int i = 0; i < 2; ++i)
#pragma unroll
            for (int j = 0; j < 2; ++j) {
                acc[i][j] = __builtin_amdgcn_mfma_f32_16x16x32_bf16(ah[i], bhf[j], acc[i][j], 0, 0, 0);
                acc[i][j] = __builtin_amdgcn_mfma_f32_16x16x32_bf16(ah[i], blf[j], acc[i][j], 0, 0, 0);
                acc[i][j] = __builtin_amdgcn_mfma_f32_16x16x32_bf16(al[i], bhf[j], acc[i][j], 0, 0, 0);
            }
    }
#pragma unroll
    for (int j = 0; j < 2; ++j) {
        const int col = col_base + j * 16 + r_lo;
        const float bb = bias[col];
#pragma unroll
        for (int i = 0; i < 2; ++i) {
#pragma unroll
            for (int r2 = 0; r2 < 4; ++r2) {
                const int row = row_base + i * 16 + kg * 4 + r2;
                xb[(long)row * E_ + col] = acc[i][j][r2] + bb;
            }
        }
    }
}

// ---------------- Kernel C: theta logit-difference GEMM (split-bf16 MFMA) ----------
__global__ __launch_bounds__(256) void k_theta_gemm(const float* __restrict__ X,
                                                    const float* __restrict__ thW,
                                                    const float* __restrict__ thb,
                                                    float* __restrict__ Sm) {
    const int tid  = threadIdx.x;
    const int wid  = tid >> 6;
    const int lane = tid & 63;
    const int r_lo = lane & 15;
    const int kg   = lane >> 4;
    const int row_base = blockIdx.x * 64 + (wid >> 1) * 32;
    const int col_base = blockIdx.y * 64 + (wid & 1) * 32;

    f32x4 acc[2][2] = {};

#pragma unroll 2
    for (int kt = 0; kt < E_; kt += 32) {
        const int ks = kt + kg * 8;
        short8 ah[2], al[2], bhf[2], blf[2];
#pragma unroll
        for (int i = 0; i < 2; ++i) {
            const int row = row_base + i * 16 + r_lo;
            const float4 v0 = *reinterpret_cast<const float4*>(&X[(long)row * E_ + ks]);
            const float4 v1 = *reinterpret_cast<const float4*>(&X[(long)row * E_ + ks + 4]);
            const float rr[8] = {v0.x, v0.y, v0.z, v0.w, v1.x, v1.y, v1.z, v1.w};
            split8(rr, ah[i], al[i]);
        }
#pragma unroll
        for (int j = 0; j < 2; ++j) {
            int n = col_base + j * 16 + r_lo;
            if (n > NN - 1) n = NN - 1;
            const float* bp = thW + (long)n * (2 * E_) + ks * 2;
            const float4 q0 = *reinterpret_cast<const float4*>(bp);
            const float4 q1 = *reinterpret_cast<const float4*>(bp + 4);
            const float4 q2 = *reinterpret_cast<const float4*>(bp + 8);
            const float4 q3 = *reinterpret_cast<const float4*>(bp + 12);
            const float rr[8] = {q0.y - q0.x, q0.w - q0.z, q1.y - q1.x, q1.w - q1.z,
                                 q2.y - q2.x, q2.w - q2.z, q3.y - q3.x, q3.w - q3.z};
            split8(rr, bhf[j], blf[j]);
        }
#pragma unroll
        for (int i = 0; i < 2; ++i)
#pragma unroll
            for (int j = 0; j < 2; ++j) {
                acc[i][j] = __builtin_amdgcn_mfma_f32_16x16x32_bf16(ah[i], bhf[j], acc[i][j], 0, 0, 0);
                acc[i][j] = __builtin_amdgcn_mfma_f32_16x16x32_bf16(ah[i], blf[j], acc[i][j], 0, 0, 0);
                acc[i][j] = __builtin_amdgcn_mfma_f32_16x16x32_bf16(al[i], bhf[j], acc[i][j], 0, 0, 0);
            }
    }

#pragma unroll
    for (int j = 0; j < 2; ++j) {
        const int col = col_base + j * 16 + r_lo;
        const int cc = (col > NN - 1) ? (NN - 1) : col;
        const float bb = thb[2 * cc + 1] - thb[2 * cc + 0];
#pragma unroll
        for (int i = 0; i < 2; ++i) {
#pragma unroll
            for (int r2 = 0; r2 < 4; ++r2) {
                const int row = row_base + i * 16 + kg * 4 + r2;
                if (col < NN) {
                    Sm[(long)row * NN + col] = acc[i][j][r2] + bb;
                }
            }
        }
    }
}

// ---------------- Kernel D: tree cumulative-product of path sigmoids ----------------
__global__ __launch_bounds__(256) void k_leaf_tree(const float* __restrict__ Sm,
                                                   float* __restrict__ out) {
    __shared__ float buf[2][L_];
    const int b = blockIdx.x;
    const int tid = threadIdx.x;
    const float* srow = Sm + b * NN;
    if (tid == 0) buf[0][0] = 1.f;
    __syncthreads();
    int cur = 0;
    for (int t = 0; t < D_; ++t) {
        const int cnt = 1 << t;
        const int base = cnt - 1;
        for (int j = tid; j < cnt; j += 256) {
            const float z = srow[base + j];
            const float s = 1.f / (1.f + __expf(-z));
            const float a = buf[cur][j];
            buf[cur ^ 1][2*j + 1] = a * s;
            buf[cur ^ 1][2*j + 0] = a - a * s;
        }
        __syncthreads();
        cur ^= 1;
    }
    reinterpret_cast<float4*>(out + b * L_)[tid] =
        reinterpret_cast<const float4*>(buf[cur])[tid];
}

extern "C" void kernel_launch(void* const* d_in, const int* in_sizes, int n_in,
                              void* d_out, int out_size, void* d_ws, size_t ws_size,
                              hipStream_t stream) {
    const int*   ids = (const int*)d_in[0];
    const float* emb = (const float*)d_in[1];
    const float* Wh  = (const float*)d_in[2];
    const float* bh  = (const float*)d_in[3];
    const float* thW = (const float*)d_in[4];
    const float* thb = (const float*)d_in[5];
    float* out = (float*)d_out;

    char* ws = (char*)d_ws;
    float* xa = (float*)(ws);                      // 2 MB
    float* xb = (float*)(ws + (2u << 20));         // 2 MB
    float* sm = (float*)(ws + (4u << 20));         // ~4.19 MB
    const size_t QS = 0x140000;                    // 1.25 MB per 513x512 normal slot
    float* Q0 = (float*)(ws + (9u << 20));             // P2
    float* Q1 = (float*)(ws + (9u << 20) + QS);        // P4
    float* Q2 = (float*)(ws + (9u << 20) + 2 * QS);    // P8
    float* Q3 = (float*)(ws + (9u << 20) + 3 * QS);    // P10
    float* T0 = (float*)(ws + (16u << 20));                  // P2^T
    float* T1 = (float*)(ws + (16u << 20) + (1u << 20));     // P4^T
    float* T2 = (float*)(ws + (16u << 20) + (2u << 20));     // P8^T
    float* T3 = (float*)(ws + (16u << 20) + (3u << 20));     // P10^T

    // 1) compose chain with embed quarters riding along (4 launches, embed hidden)
    for (int step = 0; step < 4; ++step) {
        k_fused<<<CBLK + 256, 256, 0, stream>>>(step, Wh, bh,
                                                Q0, T0, Q1, T1, Q2, T2, Q3, T3,
                                                ids, emb, xa);
    }

    // 2) batch apply: xb = xa @ M10 + c10
    k_apply<<<dim3(B_/64, E_/64), 256, 0, stream>>>(xa, T3, Q3 + (long)E_*E_, xb);

    // 3) theta logit-difference GEMM
    k_theta_gemm<<<dim3(B_/64, (NN + 63)/64), 256, 0, stream>>>(xb, thW, thb, sm);

    // 4) leaf products via tree
    k_leaf_tree<<<B_, 256, 0, stream>>>(sm, out);
}

// Round 7
// 105.550 us; speedup vs baseline: 2.2226x; 1.4164x over previous
//
#include <hip/hip_runtime.h>
#include <math.h>

#define B_  1024
#define S_  50
#define E_  512
#define L_  1024
#define D_  10
#define NN  1023   // N_NODES
#define LN_EPS 1e-5f
#define CBLK 72    // compose tile blocks (9 x 8 of 64x64 over 513x512)

typedef short short8 __attribute__((ext_vector_type(8)));
typedef float f32x4  __attribute__((ext_vector_type(4)));

union PackU { unsigned int u[4]; short8 s; };

// Split 8 f32 into bf16 hi (truncation; lo captures remainder exactly) and
// bf16 lo (RNE). 3-term product error ~2^-16, 4-term ~2^-17.
__device__ inline void split8(const float r[8], short8& hi, short8& lo) {
    PackU H, L;
#pragma unroll
    for (int q = 0; q < 4; ++q) {
        const unsigned int u0 = __float_as_uint(r[2*q+0]);
        const unsigned int u1 = __float_as_uint(r[2*q+1]);
        H.u[q] = (u0 >> 16) | (u1 & 0xFFFF0000u);
        const float h0 = __uint_as_float(u0 & 0xFFFF0000u);
        const float h1 = __uint_as_float(u1 & 0xFFFF0000u);
        const float l0 = r[2*q+0] - h0;
        const float l1 = r[2*q+1] - h1;
        unsigned int p;
        asm("v_cvt_pk_bf16_f32 %0, %1, %2" : "=v"(p) : "v"(l0), "v"(l1));
        L.u[q] = p;
    }
    hi = H.s; lo = L.s;
}

// ---------------- pipelined 64x64 GEMM tile core (K=512, k-contig A and B) ----------
struct FragBuf { float4 a[2][2]; float4 b[2][2]; };

__device__ inline void loadbuf(FragBuf& f,
                               const float* pa0, const float* pa1,
                               const float* pb0, const float* pb1, int off) {
    f.a[0][0] = *reinterpret_cast<const float4*>(pa0 + off);
    f.a[0][1] = *reinterpret_cast<const float4*>(pa0 + off + 4);
    f.a[1][0] = *reinterpret_cast<const float4*>(pa1 + off);
    f.a[1][1] = *reinterpret_cast<const float4*>(pa1 + off + 4);
    f.b[0][0] = *reinterpret_cast<const float4*>(pb0 + off);
    f.b[0][1] = *reinterpret_cast<const float4*>(pb0 + off + 4);
    f.b[1][0] = *reinterpret_cast<const float4*>(pb1 + off);
    f.b[1][1] = *reinterpret_cast<const float4*>(pb1 + off + 4);
}

template<int TERMS>
__device__ inline void compbuf(const FragBuf& f, f32x4 acc[2][2]) {
    short8 ah[2], al[2], bh[2], bl[2];
#pragma unroll
    for (int i = 0; i < 2; ++i) {
        const float ra[8] = {f.a[i][0].x, f.a[i][0].y, f.a[i][0].z, f.a[i][0].w,
                             f.a[i][1].x, f.a[i][1].y, f.a[i][1].z, f.a[i][1].w};
        split8(ra, ah[i], al[i]);
        const float rb[8] = {f.b[i][0].x, f.b[i][0].y, f.b[i][0].z, f.b[i][0].w,
                             f.b[i][1].x, f.b[i][1].y, f.b[i][1].z, f.b[i][1].w};
        split8(rb, bh[i], bl[i]);
    }
#pragma unroll
    for (int i = 0; i < 2; ++i)
#pragma unroll
        for (int j = 0; j < 2; ++j) {
            acc[i][j] = __builtin_amdgcn_mfma_f32_16x16x32_bf16(ah[i], bh[j], acc[i][j], 0, 0, 0);
            acc[i][j] = __builtin_amdgcn_mfma_f32_16x16x32_bf16(ah[i], bl[j], acc[i][j], 0, 0, 0);
            acc[i][j] = __builtin_amdgcn_mfma_f32_16x16x32_bf16(al[i], bh[j], acc[i][j], 0, 0, 0);
            if (TERMS == 4)
                acc[i][j] = __builtin_amdgcn_mfma_f32_16x16x32_bf16(al[i], bl[j], acc[i][j], 0, 0, 0);
        }
}

template<int TERMS>
__device__ inline void gemm_k512(const float* pa0, const float* pa1,
                                 const float* pb0, const float* pb1,
                                 f32x4 acc[2][2]) {
    FragBuf f0, f1;
    loadbuf(f0, pa0, pa1, pb0, pb1, 0);
#pragma unroll 1
    for (int kt = 0; kt < 16; kt += 2) {
        loadbuf(f1, pa0, pa1, pb0, pb1, (kt + 1) * 32);
        compbuf<TERMS>(f0, acc);
        if (kt + 2 < 16) loadbuf(f0, pa0, pa1, pb0, pb1, (kt + 2) * 32);
        compbuf<TERMS>(f1, acc);
    }
}

// ---------------- embed row: one block = one batch row ------------------------------
__device__ inline void do_embed_row(const int* __restrict__ ids,
                                    const float* __restrict__ emb,
                                    float* __restrict__ x, int b) {
    const int t = threadIdx.x;
    float a0 = 0.f, a1 = 0.f;
    const int* idr = ids + b * S_;
#pragma unroll 5
    for (int s = 0; s < S_; ++s) {
        const float2 v = *reinterpret_cast<const float2*>(emb + (long)idr[s] * E_ + 2 * t);
        a0 += v.x;
        a1 += v.y;
    }
    a0 *= (1.f / S_);
    a1 *= (1.f / S_);

    __shared__ float red[256];
    red[t] = a0 + a1;
    __syncthreads();
    for (int off = 128; off > 0; off >>= 1) {
        if (t < off) red[t] += red[t + off];
        __syncthreads();
    }
    const float mean = red[0] * (1.f / E_);
    __syncthreads();
    const float d0 = a0 - mean, d1 = a1 - mean;
    red[t] = d0 * d0 + d1 * d1;
    __syncthreads();
    for (int off = 128; off > 0; off >>= 1) {
        if (t < off) red[t] += red[t + off];
        __syncthreads();
    }
    const float var = red[0] * (1.f / E_);
    const float inv = 1.f / sqrtf(var + LN_EPS);
    float2 o; o.x = d0 * inv; o.y = d1 * inv;
    *reinterpret_cast<float2*>(x + b * E_ + 2 * t) = o;
}

// ---------------- Dpack: D[n][k] = thW[n][k][1] - thW[n][k][0]  (n-major, k-contig) --
__device__ inline void do_dpack(const float* __restrict__ thW,
                                float* __restrict__ Dm, int part) {
    const int total = NN * 256;           // float4-loads (2 diffs each)
    const int nth = 64 * 256;
    for (int p = part * 256 + (int)threadIdx.x; p < total; p += nth) {
        const int n = p >> 8;
        const int kp = p & 255;
        const float4 v = *reinterpret_cast<const float4*>(thW + (long)n * 1024 + kp * 4);
        float2 d; d.x = v.y - v.x; d.y = v.w - v.z;
        *reinterpret_cast<float2*>(Dm + (long)n * E_ + kp * 2) = d;
    }
}

// ---------------- compose0: P2 = [Wh;bh] ∘ [Wh;bh]  (strided B, 4-term) -------------
__device__ inline void do_compose0(const float* __restrict__ Wh, const float* __restrict__ bh,
                                   float* __restrict__ Q0, float* __restrict__ T0, int bid) {
    const int tid  = threadIdx.x;
    const int wid  = tid >> 6;
    const int lane = tid & 63;
    const int r_lo = lane & 15;
    const int kg   = lane >> 4;
    const int row_base = (bid >> 3) * 64 + (wid >> 1) * 32;
    const int col_base = (bid & 7) * 64 + (wid & 1) * 32;
    f32x4 acc[2][2] = {};
#pragma unroll 2
    for (int kt = 0; kt < E_; kt += 32) {
        const int ks = kt + kg * 8;
        short8 ah[2], al[2], bhf[2], blf[2];
#pragma unroll
        for (int i = 0; i < 2; ++i) {
            const int row = row_base + i * 16 + r_lo;
            const float* ap = (row < E_) ? (Wh + (long)row * E_ + ks) : (bh + ks);
            const float4 v0 = *reinterpret_cast<const float4*>(ap);
            const float4 v1 = *reinterpret_cast<const float4*>(ap + 4);
            const float rr[8] = {v0.x, v0.y, v0.z, v0.w, v1.x, v1.y, v1.z, v1.w};
            split8(rr, ah[i], al[i]);
        }
#pragma unroll
        for (int j = 0; j < 2; ++j) {
            const int c = col_base + j * 16 + r_lo;
            float rr[8];
#pragma unroll
            for (int q = 0; q < 8; ++q) rr[q] = Wh[(long)(ks + q) * E_ + c];
            split8(rr, bhf[j], blf[j]);
        }
#pragma unroll
        for (int i = 0; i < 2; ++i)
#pragma unroll
            for (int j = 0; j < 2; ++j) {
                acc[i][j] = __builtin_amdgcn_mfma_f32_16x16x32_bf16(ah[i], bhf[j], acc[i][j], 0, 0, 0);
                acc[i][j] = __builtin_amdgcn_mfma_f32_16x16x32_bf16(ah[i], blf[j], acc[i][j], 0, 0, 0);
                acc[i][j] = __builtin_amdgcn_mfma_f32_16x16x32_bf16(al[i], bhf[j], acc[i][j], 0, 0, 0);
                acc[i][j] = __builtin_amdgcn_mfma_f32_16x16x32_bf16(al[i], blf[j], acc[i][j], 0, 0, 0);
            }
    }
#pragma unroll
    for (int j = 0; j < 2; ++j) {
        const int col = col_base + j * 16 + r_lo;
        const float bb = bh[col];
#pragma unroll
        for (int i = 0; i < 2; ++i) {
            const int row0 = row_base + i * 16 + kg * 4;
            float4 tv;
#pragma unroll
            for (int r2 = 0; r2 < 4; ++r2) {
                const int row = row0 + r2;
                float v = acc[i][j][r2];
                if (row == E_) v += bb;
                if (row <= E_) Q0[(long)row * E_ + col] = v;
                ((float*)&tv)[r2] = v;
            }
            if (row0 + 3 < E_) {
                *reinterpret_cast<float4*>(T0 + (long)col * E_ + row0) = tv;
            }
        }
    }
}

// ---------------- compose (pipelined): C = A(513x512) ∘then B via Bt ----------------
__device__ inline void do_compose(const float* __restrict__ A,
                                  const float* __restrict__ Bt,
                                  const float* __restrict__ Bbias,
                                  float* __restrict__ C, float* __restrict__ Ct,
                                  int bid) {
    const int tid  = threadIdx.x;
    const int wid  = tid >> 6;
    const int lane = tid & 63;
    const int r_lo = lane & 15;
    const int kg   = lane >> 4;
    const int row_base = (bid >> 3) * 64 + (wid >> 1) * 32;
    const int col_base = (bid & 7) * 64 + (wid & 1) * 32;

    int ra0 = row_base + r_lo;        if (ra0 > E_) ra0 = E_;
    int ra1 = row_base + 16 + r_lo;   if (ra1 > E_) ra1 = E_;
    const float* pa0 = A + (long)ra0 * E_ + kg * 8;
    const float* pa1 = A + (long)ra1 * E_ + kg * 8;
    const float* pb0 = Bt + (long)(col_base + r_lo) * E_ + kg * 8;
    const float* pb1 = Bt + (long)(col_base + 16 + r_lo) * E_ + kg * 8;

    f32x4 acc[2][2] = {};
    gemm_k512<4>(pa0, pa1, pb0, pb1, acc);

#pragma unroll
    for (int j = 0; j < 2; ++j) {
        const int col = col_base + j * 16 + r_lo;
        const float bb = Bbias[col];
#pragma unroll
        for (int i = 0; i < 2; ++i) {
            const int row0 = row_base + i * 16 + kg * 4;
            float4 tv;
#pragma unroll
            for (int r2 = 0; r2 < 4; ++r2) {
                const int row = row0 + r2;
                float v = acc[i][j][r2];
                if (row == E_) v += bb;
                if (row <= E_) C[(long)row * E_ + col] = v;
                ((float*)&tv)[r2] = v;
            }
            if (row0 + 3 < E_) {
                *reinterpret_cast<float4*>(Ct + (long)col * E_ + row0) = tv;
            }
        }
    }
}

// ---------------- apply (pipelined): Y = X(1024x512) @ M + c  via Mt ----------------
__device__ inline void do_apply(const float* __restrict__ X,
                                const float* __restrict__ Mt,
                                const float* __restrict__ bias,
                                float* __restrict__ Y,
                                int tr, int tc) {
    const int tid  = threadIdx.x;
    const int wid  = tid >> 6;
    const int lane = tid & 63;
    const int r_lo = lane & 15;
    const int kg   = lane >> 4;
    const int row_base = tr * 64 + (wid >> 1) * 32;
    const int col_base = tc * 64 + (wid & 1) * 32;

    const float* pa0 = X + (long)(row_base + r_lo) * E_ + kg * 8;
    const float* pa1 = X + (long)(row_base + 16 + r_lo) * E_ + kg * 8;
    const float* pb0 = Mt + (long)(col_base + r_lo) * E_ + kg * 8;
    const float* pb1 = Mt + (long)(col_base + 16 + r_lo) * E_ + kg * 8;

    f32x4 acc[2][2] = {};
    gemm_k512<3>(pa0, pa1, pb0, pb1, acc);

#pragma unroll
    for (int j = 0; j < 2; ++j) {
        const int col = col_base + j * 16 + r_lo;
        const float bb = bias[col];
#pragma unroll
        for (int i = 0; i < 2; ++i) {
#pragma unroll
            for (int r2 = 0; r2 < 4; ++r2) {
                const int row = row_base + i * 16 + kg * 4 + r2;
                Y[(long)row * E_ + col] = acc[i][j][r2] + bb;
            }
        }
    }
}

// ---------------- fused kernels -----------------------------------------------------
__global__ __launch_bounds__(256) void k_fused0(const float* __restrict__ Wh,
                                                const float* __restrict__ bh,
                                                float* __restrict__ Q0, float* __restrict__ T0,
                                                const int* __restrict__ ids,
                                                const float* __restrict__ emb,
                                                float* __restrict__ xa,
                                                const float* __restrict__ thW,
                                                float* __restrict__ Dm) {
    const int bid = blockIdx.x;
    if (bid < CBLK)            do_compose0(Wh, bh, Q0, T0, bid);
    else if (bid < CBLK + 512) do_embed_row(ids, emb, xa, bid - CBLK);
    else                       do_dpack(thW, Dm, bid - CBLK - 512);
}

__global__ __launch_bounds__(256) void k_fused1(const float* __restrict__ Q0,
                                                const float* __restrict__ T0,
                                                float* __restrict__ Q1, float* __restrict__ T1,
                                                const int* __restrict__ ids,
                                                const float* __restrict__ emb,
                                                float* __restrict__ xa) {
    const int bid = blockIdx.x;
    if (bid < CBLK) do_compose(Q0, T0, Q0 + (long)E_ * E_, Q1, T1, bid);   // P4 = P2∘P2
    else            do_embed_row(ids, emb, xa, 512 + (bid - CBLK));
}

__global__ __launch_bounds__(256) void k_fused2(const float* __restrict__ Q1,
                                                const float* __restrict__ T1,
                                                float* __restrict__ Q2, float* __restrict__ T2,
                                                const float* __restrict__ xa,
                                                const float* __restrict__ T0,
                                                const float* __restrict__ Q0,
                                                float* __restrict__ y1) {
    const int bid = blockIdx.x;
    if (bid < CBLK) {
        do_compose(Q1, T1, Q1 + (long)E_ * E_, Q2, T2, bid);               // P8 = P4∘P4
    } else {
        const int t = bid - CBLK;                                          // y1 = xa@M2+c2
        do_apply(xa, T0, Q0 + (long)E_ * E_, y1, t >> 3, t & 7);
    }
}

__global__ __launch_bounds__(256) void k_apply8(const float* __restrict__ y1,
                                                const float* __restrict__ T2,
                                                const float* __restrict__ Q2,
                                                float* __restrict__ y2) {
    do_apply(y1, T2, Q2 + (long)E_ * E_, y2, blockIdx.x >> 3, blockIdx.x & 7);
}

// ---------------- theta: sm = y2 @ D^T + dthb  (D n-major k-contig) -----------------
__global__ __launch_bounds__(256) void k_theta(const float* __restrict__ X,
                                               const float* __restrict__ Dm,
                                               const float* __restrict__ thb,
                                               float* __restrict__ Sm) {
    const int tid  = threadIdx.x;
    const int wid  = tid >> 6;
    const int lane = tid & 63;
    const int r_lo = lane & 15;
    const int kg   = lane >> 4;
    const int tr = blockIdx.x >> 4;
    const int tc = blockIdx.x & 15;
    const int row_base = tr * 64 + (wid >> 1) * 32;
    const int col_base = tc * 64 + (wid & 1) * 32;

    int c0 = col_base + r_lo;        if (c0 > NN - 1) c0 = NN - 1;
    int c1 = col_base + 16 + r_lo;   if (c1 > NN - 1) c1 = NN - 1;
    const float* pa0 = X + (long)(row_base + r_lo) * E_ + kg * 8;
    const float* pa1 = X + (long)(row_base + 16 + r_lo) * E_ + kg * 8;
    const float* pb0 = Dm + (long)c0 * E_ + kg * 8;
    const float* pb1 = Dm + (long)c1 * E_ + kg * 8;

    f32x4 acc[2][2] = {};
    gemm_k512<3>(pa0, pa1, pb0, pb1, acc);

#pragma unroll
    for (int j = 0; j < 2; ++j) {
        const int col = col_base + j * 16 + r_lo;
        const int cc = (col > NN - 1) ? (NN - 1) : col;
        const float bb = thb[2 * cc + 1] - thb[2 * cc + 0];
#pragma unroll
        for (int i = 0; i < 2; ++i) {
#pragma unroll
            for (int r2 = 0; r2 < 4; ++r2) {
                const int row = row_base + i * 16 + kg * 4 + r2;
                if (col < NN) {
                    Sm[(long)row * NN + col] = acc[i][j][r2] + bb;
                }
            }
        }
    }
}

// ---------------- leaf: tree cumulative-product of path sigmoids --------------------
__global__ __launch_bounds__(256) void k_leaf_tree(const float* __restrict__ Sm,
                                                   float* __restrict__ out) {
    __shared__ float buf[2][L_];
    const int b = blockIdx.x;
    const int tid = threadIdx.x;
    const float* srow = Sm + b * NN;
    if (tid == 0) buf[0][0] = 1.f;
    __syncthreads();
    int cur = 0;
    for (int t = 0; t < D_; ++t) {
        const int cnt = 1 << t;
        const int base = cnt - 1;
        for (int j = tid; j < cnt; j += 256) {
            const float z = srow[base + j];
            const float s = 1.f / (1.f + __expf(-z));
            const float a = buf[cur][j];
            buf[cur ^ 1][2*j + 1] = a * s;
            buf[cur ^ 1][2*j + 0] = a - a * s;
        }
        __syncthreads();
        cur ^= 1;
    }
    reinterpret_cast<float4*>(out + b * L_)[tid] =
        reinterpret_cast<const float4*>(buf[cur])[tid];
}

extern "C" void kernel_launch(void* const* d_in, const int* in_sizes, int n_in,
                              void* d_out, int out_size, void* d_ws, size_t ws_size,
                              hipStream_t stream) {
    const int*   ids = (const int*)d_in[0];
    const float* emb = (const float*)d_in[1];
    const float* Wh  = (const float*)d_in[2];
    const float* bh  = (const float*)d_in[3];
    const float* thW = (const float*)d_in[4];
    const float* thb = (const float*)d_in[5];
    float* out = (float*)d_out;

    char* ws = (char*)d_ws;
    float* xa = (float*)(ws);                          // 2 MB
    float* y1 = (float*)(ws + (2u << 20));             // 2 MB
    float* y2 = (float*)(ws + (4u << 20));             // 2 MB
    float* sm = (float*)(ws + (6u << 20));             // ~4.19 MB
    float* Dm = (float*)(ws + (11u << 20));            // ~2.1 MB
    const size_t QS = 0x140000;                        // 1.25 MB per 513x512 slot
    float* Q0 = (float*)(ws + (14u << 20));            // P2
    float* Q1 = (float*)(ws + (14u << 20) + QS);       // P4
    float* Q2 = (float*)(ws + (14u << 20) + 2 * QS);   // P8
    float* T0 = (float*)(ws + (20u << 20));            // P2^T (1 MB)
    float* T1 = (float*)(ws + (21u << 20));            // P4^T
    float* T2 = (float*)(ws + (22u << 20));            // P8^T

    // 1) P2 compose + embed rows 0-511 + Dpack
    k_fused0<<<CBLK + 512 + 64, 256, 0, stream>>>(Wh, bh, Q0, T0, ids, emb, xa, thW, Dm);

    // 2) P4 compose + embed rows 512-1023
    k_fused1<<<CBLK + 512, 256, 0, stream>>>(Q0, T0, Q1, T1, ids, emb, xa);

    // 3) P8 compose + y1 = xa@M2 + c2
    k_fused2<<<CBLK + 128, 256, 0, stream>>>(Q1, T1, Q2, T2, xa, T0, Q0, y1);

    // 4) y2 = y1@M8 + c8
    k_apply8<<<128, 256, 0, stream>>>(y1, T2, Q2, y2);

    // 5) sm = y2 @ dTheta + dthb
    k_theta<<<256, 256, 0, stream>>>(y2, Dm, thb, sm);

    // 6) leaf products via tree
    k_leaf_tree<<<B_, 256, 0, stream>>>(sm, out);
}

// Round 8
// 105.177 us; speedup vs baseline: 2.2304x; 1.0035x over previous
//
#include <hip/hip_runtime.h>
#include <hip/hip_bf16.h>
#include <math.h>

#define B_  1024
#define S_  50
#define E_  512
#define L_  1024
#define D_  10
#define NN  1023   // N_NODES
#define LN_EPS 1e-5f
#define CBLK 72    // compose tile blocks (9 x 8 of 64x64 over 513x512)

typedef short short8 __attribute__((ext_vector_type(8)));
typedef float f32x4  __attribute__((ext_vector_type(4)));
typedef unsigned short u16;
typedef unsigned int   u32;

union PackU { unsigned int u[4]; short8 s; };

// Split 8 f32 into bf16 hi (truncation; lo captures remainder exactly) and
// bf16 lo (RNE). Used only where inputs are raw f32 (compose0).
__device__ inline void split8(const float r[8], short8& hi, short8& lo) {
    PackU H, L;
#pragma unroll
    for (int q = 0; q < 4; ++q) {
        const unsigned int u0 = __float_as_uint(r[2*q+0]);
        const unsigned int u1 = __float_as_uint(r[2*q+1]);
        H.u[q] = (u0 >> 16) | (u1 & 0xFFFF0000u);
        const float h0 = __uint_as_float(u0 & 0xFFFF0000u);
        const float h1 = __uint_as_float(u1 & 0xFFFF0000u);
        const float l0 = r[2*q+0] - h0;
        const float l1 = r[2*q+1] - h1;
        unsigned int p;
        asm("v_cvt_pk_bf16_f32 %0, %1, %2" : "=v"(p) : "v"(l0), "v"(l1));
        L.u[q] = p;
    }
    hi = H.s; lo = L.s;
}

// Split one f32 -> (hi trunc bf16, lo RNE bf16). Identical values to split8.
__device__ inline void split1(float v, u16& h, u16& l) {
    const unsigned int u = __float_as_uint(v);
    h = (u16)(u >> 16);
    const float hf = __uint_as_float(u & 0xFFFF0000u);
    const float lo = v - hf;
    unsigned int p;
    asm("v_cvt_pk_bf16_f32 %0, %1, %2" : "=v"(p) : "v"(lo), "v"(lo));
    l = (u16)(p & 0xFFFFu);
}

// Split a pair -> packed hi word + packed lo word (elements [2t],[2t+1]).
__device__ inline void split2(float v0, float v1, u32& hw, u32& lw) {
    const unsigned int u0 = __float_as_uint(v0);
    const unsigned int u1 = __float_as_uint(v1);
    hw = (u0 >> 16) | (u1 & 0xFFFF0000u);
    const float h0 = __uint_as_float(u0 & 0xFFFF0000u);
    const float h1 = __uint_as_float(u1 & 0xFFFF0000u);
    const float l0 = v0 - h0;
    const float l1 = v1 - h1;
    asm("v_cvt_pk_bf16_f32 %0, %1, %2" : "=v"(lw) : "v"(l0), "v"(l1));
}

// ---------------- bf16-plane pipelined 64x64 GEMM core (K=512) ----------------------
struct BFrag { short8 ah[2], al[2], bh[2], bl[2]; };

__device__ inline void loadB(BFrag& f,
                             const u16* pah0, const u16* pal0,
                             const u16* pah1, const u16* pal1,
                             const u16* pbh0, const u16* pbl0,
                             const u16* pbh1, const u16* pbl1, int off) {
    f.ah[0] = *reinterpret_cast<const short8*>(pah0 + off);
    f.al[0] = *reinterpret_cast<const short8*>(pal0 + off);
    f.ah[1] = *reinterpret_cast<const short8*>(pah1 + off);
    f.al[1] = *reinterpret_cast<const short8*>(pal1 + off);
    f.bh[0] = *reinterpret_cast<const short8*>(pbh0 + off);
    f.bl[0] = *reinterpret_cast<const short8*>(pbl0 + off);
    f.bh[1] = *reinterpret_cast<const short8*>(pbh1 + off);
    f.bl[1] = *reinterpret_cast<const short8*>(pbl1 + off);
}

template<int TERMS>
__device__ inline void compB(const BFrag& f, f32x4 acc[2][2]) {
#pragma unroll
    for (int i = 0; i < 2; ++i)
#pragma unroll
        for (int j = 0; j < 2; ++j) {
            acc[i][j] = __builtin_amdgcn_mfma_f32_16x16x32_bf16(f.ah[i], f.bh[j], acc[i][j], 0, 0, 0);
            acc[i][j] = __builtin_amdgcn_mfma_f32_16x16x32_bf16(f.ah[i], f.bl[j], acc[i][j], 0, 0, 0);
            acc[i][j] = __builtin_amdgcn_mfma_f32_16x16x32_bf16(f.al[i], f.bh[j], acc[i][j], 0, 0, 0);
            if (TERMS == 4)
                acc[i][j] = __builtin_amdgcn_mfma_f32_16x16x32_bf16(f.al[i], f.bl[j], acc[i][j], 0, 0, 0);
        }
}

template<int TERMS>
__device__ inline void gemmB(const u16* pah0, const u16* pal0,
                             const u16* pah1, const u16* pal1,
                             const u16* pbh0, const u16* pbl0,
                             const u16* pbh1, const u16* pbl1,
                             f32x4 acc[2][2]) {
    BFrag f0, f1;
    loadB(f0, pah0, pal0, pah1, pal1, pbh0, pbl0, pbh1, pbl1, 0);
#pragma unroll 1
    for (int kt = 0; kt < 16; kt += 2) {
        loadB(f1, pah0, pal0, pah1, pal1, pbh0, pbl0, pbh1, pbl1, (kt + 1) * 32);
        compB<TERMS>(f0, acc);
        if (kt + 2 < 16) loadB(f0, pah0, pal0, pah1, pal1, pbh0, pbl0, pbh1, pbl1, (kt + 2) * 32);
        compB<TERMS>(f1, acc);
    }
}

// ---------------- embed row: one block = one batch row, writes bf16 planes ---------
__device__ inline void do_embed_row(const int* __restrict__ ids,
                                    const float* __restrict__ emb,
                                    u16* __restrict__ xah, u16* __restrict__ xal, int b) {
    const int t = threadIdx.x;
    float a0 = 0.f, a1 = 0.f;
    const int* idr = ids + b * S_;
#pragma unroll 5
    for (int s = 0; s < S_; ++s) {
        const float2 v = *reinterpret_cast<const float2*>(emb + (long)idr[s] * E_ + 2 * t);
        a0 += v.x;
        a1 += v.y;
    }
    a0 *= (1.f / S_);
    a1 *= (1.f / S_);

    __shared__ float red[256];
    red[t] = a0 + a1;
    __syncthreads();
    for (int off = 128; off > 0; off >>= 1) {
        if (t < off) red[t] += red[t + off];
        __syncthreads();
    }
    const float mean = red[0] * (1.f / E_);
    __syncthreads();
    const float d0 = a0 - mean, d1 = a1 - mean;
    red[t] = d0 * d0 + d1 * d1;
    __syncthreads();
    for (int off = 128; off > 0; off >>= 1) {
        if (t < off) red[t] += red[t + off];
        __syncthreads();
    }
    const float var = red[0] * (1.f / E_);
    const float inv = 1.f / sqrtf(var + LN_EPS);
    u32 hw, lw;
    split2(d0 * inv, d1 * inv, hw, lw);
    *reinterpret_cast<u32*>(xah + (long)b * E_ + 2 * t) = hw;
    *reinterpret_cast<u32*>(xal + (long)b * E_ + 2 * t) = lw;
}

// ---------------- Dpack: bf16 planes of thW[n][k][1]-thW[n][k][0] -------------------
__device__ inline void do_dpack(const float* __restrict__ thW,
                                u16* __restrict__ Dh, u16* __restrict__ Dl, int part) {
    const int total = NN * 256;           // float4-loads (2 diffs each)
    const int nth = 64 * 256;
    for (int p = part * 256 + (int)threadIdx.x; p < total; p += nth) {
        const int n = p >> 8;
        const int kp = p & 255;
        const float4 v = *reinterpret_cast<const float4*>(thW + (long)n * 1024 + kp * 4);
        u32 hw, lw;
        split2(v.y - v.x, v.w - v.z, hw, lw);
        *reinterpret_cast<u32*>(Dh + (long)n * E_ + kp * 2) = hw;
        *reinterpret_cast<u32*>(Dl + (long)n * E_ + kp * 2) = lw;
    }
}

// ---------------- shared compose epilogue: planes + transposed planes + cvec --------
__device__ inline void compose_epilogue(f32x4 acc[2][2], int row_base, int col_base,
                                        int kg, int r_lo,
                                        const float* __restrict__ Bbias,
                                        u16* __restrict__ Ch, u16* __restrict__ Cl,
                                        u16* __restrict__ Th, u16* __restrict__ Tl,
                                        float* __restrict__ cvec) {
#pragma unroll
    for (int j = 0; j < 2; ++j) {
        const int col = col_base + j * 16 + r_lo;
        const float bb = Bbias[col];
#pragma unroll
        for (int i = 0; i < 2; ++i) {
            const int row0 = row_base + i * 16 + kg * 4;
            union { ushort4 v; u16 e[4]; } th, tl;
#pragma unroll
            for (int r2 = 0; r2 < 4; ++r2) {
                const int row = row0 + r2;
                float v = acc[i][j][r2];
                if (row == E_) { v += bb; cvec[col] = v; }
                u16 h, l;
                split1(v, h, l);
                if (row <= E_ && Ch != nullptr) {
                    Ch[(long)row * E_ + col] = h;
                    Cl[(long)row * E_ + col] = l;
                }
                th.e[r2] = h; tl.e[r2] = l;
            }
            if (row0 + 3 < E_) {
                *reinterpret_cast<ushort4*>(Th + (long)col * E_ + row0) = th.v;
                *reinterpret_cast<ushort4*>(Tl + (long)col * E_ + row0) = tl.v;
            }
        }
    }
}

// ---------------- compose0: P2 = [Wh;bh] ∘ [Wh;bh]  (f32 inputs, 4-term) ------------
__device__ inline void do_compose0(const float* __restrict__ Wh, const float* __restrict__ bh,
                                   u16* __restrict__ Ch, u16* __restrict__ Cl,
                                   u16* __restrict__ Th, u16* __restrict__ Tl,
                                   float* __restrict__ cvec, int bid) {
    const int tid  = threadIdx.x;
    const int wid  = tid >> 6;
    const int lane = tid & 63;
    const int r_lo = lane & 15;
    const int kg   = lane >> 4;
    const int row_base = (bid >> 3) * 64 + (wid >> 1) * 32;
    const int col_base = (bid & 7) * 64 + (wid & 1) * 32;
    f32x4 acc[2][2] = {};
#pragma unroll 2
    for (int kt = 0; kt < E_; kt += 32) {
        const int ks = kt + kg * 8;
        short8 ah[2], al[2], bhf[2], blf[2];
#pragma unroll
        for (int i = 0; i < 2; ++i) {
            const int row = row_base + i * 16 + r_lo;
            const float* ap = (row < E_) ? (Wh + (long)row * E_ + ks) : (bh + ks);
            const float4 v0 = *reinterpret_cast<const float4*>(ap);
            const float4 v1 = *reinterpret_cast<const float4*>(ap + 4);
            const float rr[8] = {v0.x, v0.y, v0.z, v0.w, v1.x, v1.y, v1.z, v1.w};
            split8(rr, ah[i], al[i]);
        }
#pragma unroll
        for (int j = 0; j < 2; ++j) {
            const int c = col_base + j * 16 + r_lo;
            float rr[8];
#pragma unroll
            for (int q = 0; q < 8; ++q) rr[q] = Wh[(long)(ks + q) * E_ + c];
            split8(rr, bhf[j], blf[j]);
        }
#pragma unroll
        for (int i = 0; i < 2; ++i)
#pragma unroll
            for (int j = 0; j < 2; ++j) {
                acc[i][j] = __builtin_amdgcn_mfma_f32_16x16x32_bf16(ah[i], bhf[j], acc[i][j], 0, 0, 0);
                acc[i][j] = __builtin_amdgcn_mfma_f32_16x16x32_bf16(ah[i], blf[j], acc[i][j], 0, 0, 0);
                acc[i][j] = __builtin_amdgcn_mfma_f32_16x16x32_bf16(al[i], bhf[j], acc[i][j], 0, 0, 0);
                acc[i][j] = __builtin_amdgcn_mfma_f32_16x16x32_bf16(al[i], blf[j], acc[i][j], 0, 0, 0);
            }
    }
    compose_epilogue(acc, row_base, col_base, kg, r_lo, bh, Ch, Cl, Th, Tl, cvec);
}

// ---------------- compose (bf16 planes): C = A(513x512) ∘then B ---------------------
__device__ inline void do_composeB(const u16* __restrict__ Ah, const u16* __restrict__ Al,
                                   const u16* __restrict__ Bh, const u16* __restrict__ Bl,
                                   const float* __restrict__ Bbias,
                                   u16* __restrict__ Ch, u16* __restrict__ Cl,
                                   u16* __restrict__ Th, u16* __restrict__ Tl,
                                   float* __restrict__ cvec, int bid) {
    const int tid  = threadIdx.x;
    const int wid  = tid >> 6;
    const int lane = tid & 63;
    const int r_lo = lane & 15;
    const int kg   = lane >> 4;
    const int row_base = (bid >> 3) * 64 + (wid >> 1) * 32;
    const int col_base = (bid & 7) * 64 + (wid & 1) * 32;

    int ra0 = row_base + r_lo;        if (ra0 > E_) ra0 = E_;
    int ra1 = row_base + 16 + r_lo;   if (ra1 > E_) ra1 = E_;
    const long rb0 = col_base + r_lo;
    const long rb1 = col_base + 16 + r_lo;

    f32x4 acc[2][2] = {};
    gemmB<4>(Ah + (long)ra0 * E_ + kg * 8, Al + (long)ra0 * E_ + kg * 8,
             Ah + (long)ra1 * E_ + kg * 8, Al + (long)ra1 * E_ + kg * 8,
             Bh + rb0 * E_ + kg * 8,       Bl + rb0 * E_ + kg * 8,
             Bh + rb1 * E_ + kg * 8,       Bl + rb1 * E_ + kg * 8, acc);

    compose_epilogue(acc, row_base, col_base, kg, r_lo, Bbias, Ch, Cl, Th, Tl, cvec);
}

// ---------------- apply (bf16 planes): Y = X(1024x512) @ M + c ----------------------
__device__ inline void do_applyB(const u16* __restrict__ Xh, const u16* __restrict__ Xl,
                                 const u16* __restrict__ Mh, const u16* __restrict__ Ml,
                                 const float* __restrict__ cvec,
                                 u16* __restrict__ Yh, u16* __restrict__ Yl,
                                 int tr, int tc) {
    const int tid  = threadIdx.x;
    const int wid  = tid >> 6;
    const int lane = tid & 63;
    const int r_lo = lane & 15;
    const int kg   = lane >> 4;
    const int row_base = tr * 64 + (wid >> 1) * 32;
    const int col_base = tc * 64 + (wid & 1) * 32;

    const long ra0 = row_base + r_lo;
    const long ra1 = row_base + 16 + r_lo;
    const long rb0 = col_base + r_lo;
    const long rb1 = col_base + 16 + r_lo;

    f32x4 acc[2][2] = {};
    gemmB<3>(Xh + ra0 * E_ + kg * 8, Xl + ra0 * E_ + kg * 8,
             Xh + ra1 * E_ + kg * 8, Xl + ra1 * E_ + kg * 8,
             Mh + rb0 * E_ + kg * 8, Ml + rb0 * E_ + kg * 8,
             Mh + rb1 * E_ + kg * 8, Ml + rb1 * E_ + kg * 8, acc);

#pragma unroll
    for (int j = 0; j < 2; ++j) {
        const int col = col_base + j * 16 + r_lo;
        const float bb = cvec[col];
#pragma unroll
        for (int i = 0; i < 2; ++i) {
#pragma unroll
            for (int r2 = 0; r2 < 4; ++r2) {
                const int row = row_base + i * 16 + kg * 4 + r2;
                u16 h, l;
                split1(acc[i][j][r2] + bb, h, l);
                Yh[(long)row * E_ + col] = h;
                Yl[(long)row * E_ + col] = l;
            }
        }
    }
}

// ---------------- fused kernels -----------------------------------------------------
__global__ __launch_bounds__(256) void k_fused0(const float* __restrict__ Wh,
                                                const float* __restrict__ bh,
                                                u16* __restrict__ Ch0, u16* __restrict__ Cl0,
                                                u16* __restrict__ Th0, u16* __restrict__ Tl0,
                                                float* __restrict__ cvec0,
                                                const int* __restrict__ ids,
                                                const float* __restrict__ emb,
                                                u16* __restrict__ xah, u16* __restrict__ xal,
                                                const float* __restrict__ thW,
                                                u16* __restrict__ Dh, u16* __restrict__ Dl) {
    const int bid = blockIdx.x;
    if (bid < CBLK)            do_compose0(Wh, bh, Ch0, Cl0, Th0, Tl0, cvec0, bid);
    else if (bid < CBLK + 512) do_embed_row(ids, emb, xah, xal, bid - CBLK);
    else                       do_dpack(thW, Dh, Dl, bid - CBLK - 512);
}

__global__ __launch_bounds__(256) void k_fused1(const u16* __restrict__ Ch0, const u16* __restrict__ Cl0,
                                                const u16* __restrict__ Th0, const u16* __restrict__ Tl0,
                                                const float* __restrict__ cvec0,
                                                u16* __restrict__ Ch1, u16* __restrict__ Cl1,
                                                u16* __restrict__ Th1, u16* __restrict__ Tl1,
                                                float* __restrict__ cvec1,
                                                const int* __restrict__ ids,
                                                const float* __restrict__ emb,
                                                u16* __restrict__ xah, u16* __restrict__ xal) {
    const int bid = blockIdx.x;
    if (bid < CBLK) do_composeB(Ch0, Cl0, Th0, Tl0, cvec0, Ch1, Cl1, Th1, Tl1, cvec1, bid);   // P4
    else            do_embed_row(ids, emb, xah, xal, 512 + (bid - CBLK));
}

__global__ __launch_bounds__(256) void k_fused2(const u16* __restrict__ Ch1, const u16* __restrict__ Cl1,
                                                const u16* __restrict__ Th1, const u16* __restrict__ Tl1,
                                                const float* __restrict__ cvec1,
                                                u16* __restrict__ Th2, u16* __restrict__ Tl2,
                                                float* __restrict__ cvec2,
                                                const u16* __restrict__ xah, const u16* __restrict__ xal,
                                                const u16* __restrict__ Th0, const u16* __restrict__ Tl0,
                                                const float* __restrict__ cvec0,
                                                u16* __restrict__ y1h, u16* __restrict__ y1l) {
    const int bid = blockIdx.x;
    if (bid < CBLK) {
        do_composeB(Ch1, Cl1, Th1, Tl1, cvec1, nullptr, nullptr, Th2, Tl2, cvec2, bid);       // P8
    } else {
        const int t = bid - CBLK;                                                             // y1 = xa@M2+c2
        do_applyB(xah, xal, Th0, Tl0, cvec0, y1h, y1l, t >> 3, t & 7);
    }
}

__global__ __launch_bounds__(256) void k_apply8(const u16* __restrict__ y1h, const u16* __restrict__ y1l,
                                                const u16* __restrict__ Th2, const u16* __restrict__ Tl2,
                                                const float* __restrict__ cvec2,
                                                u16* __restrict__ y2h, u16* __restrict__ y2l) {
    do_applyB(y1h, y1l, Th2, Tl2, cvec2, y2h, y2l, blockIdx.x >> 3, blockIdx.x & 7);
}

// ---------------- theta: sm = y2 @ D^T + dthb  (bf16 planes both sides) -------------
__global__ __launch_bounds__(256) void k_theta(const u16* __restrict__ Xh, const u16* __restrict__ Xl,
                                               const u16* __restrict__ Dh, const u16* __restrict__ Dl,
                                               const float* __restrict__ thb,
                                               float* __restrict__ Sm) {
    const int tid  = threadIdx.x;
    const int wid  = tid >> 6;
    const int lane = tid & 63;
    const int r_lo = lane & 15;
    const int kg   = lane >> 4;
    const int tr = blockIdx.x >> 4;
    const int tc = blockIdx.x & 15;
    const int row_base = tr * 64 + (wid >> 1) * 32;
    const int col_base = tc * 64 + (wid & 1) * 32;

    long c0 = col_base + r_lo;        if (c0 > NN - 1) c0 = NN - 1;
    long c1 = col_base + 16 + r_lo;   if (c1 > NN - 1) c1 = NN - 1;
    const long ra0 = row_base + r_lo;
    const long ra1 = row_base + 16 + r_lo;

    f32x4 acc[2][2] = {};
    gemmB<3>(Xh + ra0 * E_ + kg * 8, Xl + ra0 * E_ + kg * 8,
             Xh + ra1 * E_ + kg * 8, Xl + ra1 * E_ + kg * 8,
             Dh + c0 * E_ + kg * 8,  Dl + c0 * E_ + kg * 8,
             Dh + c1 * E_ + kg * 8,  Dl + c1 * E_ + kg * 8, acc);

#pragma unroll
    for (int j = 0; j < 2; ++j) {
        const int col = col_base + j * 16 + r_lo;
        const int cc = (col > NN - 1) ? (NN - 1) : col;
        const float bb = thb[2 * cc + 1] - thb[2 * cc + 0];
#pragma unroll
        for (int i = 0; i < 2; ++i) {
#pragma unroll
            for (int r2 = 0; r2 < 4; ++r2) {
                const int row = row_base + i * 16 + kg * 4 + r2;
                if (col < NN) {
                    Sm[(long)row * NN + col] = acc[i][j][r2] + bb;
                }
            }
        }
    }
}

// ---------------- leaf: tree cumulative-product of path sigmoids --------------------
__global__ __launch_bounds__(256) void k_leaf_tree(const float* __restrict__ Sm,
                                                   float* __restrict__ out) {
    __shared__ float buf[2][L_];
    const int b = blockIdx.x;
    const int tid = threadIdx.x;
    const float* srow = Sm + (long)b * NN;
    if (tid == 0) buf[0][0] = 1.f;
    __syncthreads();
    int cur = 0;
    for (int t = 0; t < D_; ++t) {
        const int cnt = 1 << t;
        const int base = cnt - 1;
        for (int j = tid; j < cnt; j += 256) {
            const float z = srow[base + j];
            const float s = 1.f / (1.f + __expf(-z));
            const float a = buf[cur][j];
            buf[cur ^ 1][2*j + 1] = a * s;
            buf[cur ^ 1][2*j + 0] = a - a * s;
        }
        __syncthreads();
        cur ^= 1;
    }
    reinterpret_cast<float4*>(out + (long)b * L_)[tid] =
        reinterpret_cast<const float4*>(buf[cur])[tid];
}

extern "C" void kernel_launch(void* const* d_in, const int* in_sizes, int n_in,
                              void* d_out, int out_size, void* d_ws, size_t ws_size,
                              hipStream_t stream) {
    const int*   ids = (const int*)d_in[0];
    const float* emb = (const float*)d_in[1];
    const float* Wh  = (const float*)d_in[2];
    const float* bh  = (const float*)d_in[3];
    const float* thW = (const float*)d_in[4];
    const float* thb = (const float*)d_in[5];
    float* out = (float*)d_out;

    char* ws = (char*)d_ws;
    const size_t MB = 1u << 20;
    u16* xah = (u16*)(ws + 0 * MB);        // [1024][512] bf16 hi
    u16* xal = (u16*)(ws + 1 * MB);
    u16* y1h = (u16*)(ws + 2 * MB);
    u16* y1l = (u16*)(ws + 3 * MB);
    u16* y2h = (u16*)(ws + 4 * MB);
    u16* y2l = (u16*)(ws + 5 * MB);
    float* sm = (float*)(ws + 6 * MB);     // [1024][1023] f32 (~4.19 MB)
    u16* Dh  = (u16*)(ws + 11 * MB);       // [1023][512]
    u16* Dl  = (u16*)(ws + 12 * MB);
    u16* Ch0 = (u16*)(ws + 13 * MB);       // [513][512]
    u16* Cl0 = (u16*)(ws + 14 * MB);
    u16* Ch1 = (u16*)(ws + 15 * MB);
    u16* Cl1 = (u16*)(ws + 16 * MB);
    u16* Th0 = (u16*)(ws + 17 * MB);       // [512][512] transposed planes
    u16* Tl0 = (u16*)(ws + 17 * MB + 512 * 1024);
    u16* Th1 = (u16*)(ws + 18 * MB);
    u16* Tl1 = (u16*)(ws + 18 * MB + 512 * 1024);
    u16* Th2 = (u16*)(ws + 19 * MB);
    u16* Tl2 = (u16*)(ws + 19 * MB + 512 * 1024);
    float* cvec0 = (float*)(ws + 20 * MB);
    float* cvec1 = (float*)(ws + 20 * MB + 4096);
    float* cvec2 = (float*)(ws + 20 * MB + 8192);

    // 1) P2 compose + embed rows 0-511 + Dpack
    k_fused0<<<CBLK + 512 + 64, 256, 0, stream>>>(Wh, bh, Ch0, Cl0, Th0, Tl0, cvec0,
                                                  ids, emb, xah, xal, thW, Dh, Dl);

    // 2) P4 compose + embed rows 512-1023
    k_fused1<<<CBLK + 512, 256, 0, stream>>>(Ch0, Cl0, Th0, Tl0, cvec0,
                                             Ch1, Cl1, Th1, Tl1, cvec1,
                                             ids, emb, xah, xal);

    // 3) P8 compose + y1 = xa@M2 + c2
    k_fused2<<<CBLK + 128, 256, 0, stream>>>(Ch1, Cl1, Th1, Tl1, cvec1,
                                             Th2, Tl2, cvec2,
                                             xah, xal, Th0, Tl0, cvec0, y1h, y1l);

    // 4) y2 = y1@M8 + c8
    k_apply8<<<128, 256, 0, stream>>>(y1h, y1l, Th2, Tl2, cvec2, y2h, y2l);

    // 5) sm = y2 @ dTheta + dthb
    k_theta<<<256, 256, 0, stream>>>(y2h, y2l, Dh, Dl, thb, sm);

    // 6) leaf products via tree
    k_leaf_tree<<<B_, 256, 0, stream>>>(sm, out);
}